// Round 6
// baseline (4053.658 us; speedup 1.0000x reference)
//
#include <hip/hip_runtime.h>
#include <cstddef>

#define B_    64
#define P_    196
#define E_    2048
#define H_    512
#define EMB_  512
#define V_    10000
#define TCAP_ 50
#define TMAX_ 49
#define KI_   2560   // E_ + EMB_
#define G3_   1536   // 3*H_
#define NBLK_ 1024   // persistent loop kernel grid (4 blocks/CU on 256 CUs)
#define FSTRIDE 32   // 128B spacing between barrier flag lines
#define NGO_  16
#define COLLECTOR_ (NBLK_ - 1)

typedef __attribute__((ext_vector_type(8))) short short8;
typedef __attribute__((ext_vector_type(4))) float floatx4;
typedef unsigned int u32;
typedef __attribute__((ext_vector_type(2))) unsigned int u32x2;
typedef __attribute__((ext_vector_type(4))) unsigned int u32x4;
typedef const __attribute__((address_space(1))) u32* gptr_t;
typedef __attribute__((address_space(3))) u32* lptr_t;

__device__ __forceinline__ unsigned short f2bf_rne(float f) {
    unsigned int x = __float_as_uint(f);
    unsigned int r = (x + 0x7fffu + ((x >> 16) & 1u)) >> 16;
    return (unsigned short)r;
}
__device__ __forceinline__ float bf2f(unsigned int u16) {
    return __uint_as_float(u16 << 16);
}
__device__ __forceinline__ float fast_tanh(float x) {
    float a = fabsf(x);
    float e = __expf(2.0f * a);
    float r = 1.0f - 2.0f / (e + 1.0f);
    return (x < 0.0f) ? -r : r;
}
__device__ __forceinline__ float fast_sig(float x) {
    return 1.0f / (1.0f + __expf(-x));
}

// ---- agent-coherent (sc1) scalar accessors for cross-phase data ----
__device__ __forceinline__ float ldf(const float* p) {
    return __hip_atomic_load((float*)p, __ATOMIC_RELAXED, __HIP_MEMORY_SCOPE_AGENT);
}
__device__ __forceinline__ void stf(float* p, float v) {
    __hip_atomic_store(p, v, __ATOMIC_RELAXED, __HIP_MEMORY_SCOPE_AGENT);
}
__device__ __forceinline__ void stu(u32* p, u32 v) {
    __hip_atomic_store(p, v, __ATOMIC_RELAXED, __HIP_MEMORY_SCOPE_AGENT);
}
__device__ __forceinline__ short8 cvt8(u32x4 v) {
    union { u32x4 u; short8 s; } x; x.u = v; return x.s;
}

// Vectorized coherent load: global_load_dwordx4 with sc1.
#define GLD16(dst, base, OFF) \
    asm volatile("global_load_dwordx4 %0, %1, off offset:" #OFF " sc1" \
                 : "=v"(dst) : "v"(base) : "memory")

// Fence-free grid barrier (sc1 data path). Collector = block 1023.
__device__ __forceinline__ void gbar(unsigned int* __restrict__ flags,
                                     unsigned int* __restrict__ go,
                                     unsigned int ep)
{
    asm volatile("s_waitcnt vmcnt(0)" ::: "memory");
    __syncthreads();
    if (blockIdx.x == COLLECTOR_) {
        int tid = threadIdx.x;
        for (int s = tid; s < NBLK_ - 1; s += 256) {
            while (__hip_atomic_load(&flags[s * FSTRIDE], __ATOMIC_RELAXED,
                                     __HIP_MEMORY_SCOPE_AGENT) < ep)
                __builtin_amdgcn_s_sleep(1);
        }
        __syncthreads();
        if (tid < NGO_)
            __hip_atomic_store(&go[tid * FSTRIDE], ep, __ATOMIC_RELAXED,
                               __HIP_MEMORY_SCOPE_AGENT);
    } else {
        if (threadIdx.x == 0) {
            __hip_atomic_store(&flags[blockIdx.x * FSTRIDE], ep, __ATOMIC_RELAXED,
                               __HIP_MEMORY_SCOPE_AGENT);
            while (__hip_atomic_load(&go[(blockIdx.x & (NGO_ - 1)) * FSTRIDE],
                                     __ATOMIC_RELAXED, __HIP_MEMORY_SCOPE_AGENT) < ep)
                __builtin_amdgcn_s_sleep(2);
        }
    }
    __syncthreads();
}

// ---------------- output init: zero t=49 slices, write dec, reset barrier ----------------
__global__ void init_out_kernel(float* __restrict__ preds, float* __restrict__ alphas,
                                float* __restrict__ dec, const int* __restrict__ lens,
                                unsigned int* __restrict__ flags, unsigned int* __restrict__ go)
{
    int i = blockIdx.x * 256 + threadIdx.x;
    if (i < NBLK_ * FSTRIDE) flags[i] = 0u;
    if (i < NGO_ * FSTRIDE) go[i] = 0u;
    if (i < B_ * V_) {
        int b = i / V_, v = i - b * V_;
        preds[((size_t)b * TCAP_ + TMAX_) * V_ + v] = 0.f;
    }
    if (i < B_ * P_) {
        int b = i / P_, p = i - b * P_;
        alphas[((size_t)b * TCAP_ + TMAX_) * P_ + p] = 0.f;
    }
    if (i < B_) dec[i] = (float)(lens[i] - 1);
}

// ---------------- f32 -> bf16 cast (8 elems/thread) ----------------
__global__ void f2bf_kernel(const float* __restrict__ src, unsigned short* __restrict__ dst, int n8)
{
    int i = blockIdx.x * 256 + threadIdx.x;
    if (i >= n8) return;
    float4 a = ((const float4*)src)[2 * i];
    float4 b = ((const float4*)src)[2 * i + 1];
    uint4 o;
    o.x = (unsigned)f2bf_rne(a.x) | ((unsigned)f2bf_rne(a.y) << 16);
    o.y = (unsigned)f2bf_rne(a.z) | ((unsigned)f2bf_rne(a.w) << 16);
    o.z = (unsigned)f2bf_rne(b.x) | ((unsigned)f2bf_rne(b.y) << 16);
    o.w = (unsigned)f2bf_rne(b.z) | ((unsigned)f2bf_rne(b.w) << 16);
    ((uint4*)dst)[i] = o;
}

// ---------------- mean over P, output bf16 (64 x 2048) ----------------
__global__ void mean_kernel(const float* __restrict__ f, unsigned short* __restrict__ out)
{
    int i = blockIdx.x * 256 + threadIdx.x;
    int b = i >> 11, e = i & 2047;
    const float* p = f + (size_t)b * P_ * E_ + e;
    float s = 0.f;
    #pragma unroll 4
    for (int k = 0; k < P_; ++k) s += p[(size_t)k * E_];
    out[i] = f2bf_rne(s * (1.0f / (float)P_));
}

// ---------------- xwx GEMM, LDS-staged: 128x128 tile, BK=64 ----------------
__global__ void __launch_bounds__(256)
mfma_xwx_kernel(const unsigned short* __restrict__ A,   // [12544][2048]
                const unsigned short* __restrict__ W,   // [2048][2048]
                const float* __restrict__ bias,
                unsigned short* __restrict__ C)         // [12544][2048] bf16
{
    __shared__ unsigned short As[128 * 64];
    __shared__ unsigned short Bs[128 * 64];
    int wv = threadIdx.x >> 6, lane = threadIdx.x & 63;
    int mr = lane & 15, quad = lane >> 4;
    int m0 = blockIdx.y * 128;
    int n0 = blockIdx.x * 128;
    int wm = (wv & 1) * 64, wn = (wv >> 1) * 64;
    int srow = wv * 32;
    int lrow = lane >> 3;
    int lcol = (lane & 7) * 8;
    floatx4 acc[4][4] = {};
    for (int k0 = 0; k0 < E_; k0 += 64) {
        __syncthreads();
        #pragma unroll
        for (int i = 0; i < 4; ++i) {
            int r = srow + i * 8;
            __builtin_amdgcn_global_load_lds(
                (gptr_t)(A + (size_t)(m0 + r + lrow) * E_ + k0 + lcol),
                (lptr_t)(As + r * 64), 16, 0, 0);
            __builtin_amdgcn_global_load_lds(
                (gptr_t)(W + (size_t)(n0 + r + lrow) * E_ + k0 + lcol),
                (lptr_t)(Bs + r * 64), 16, 0, 0);
        }
        __syncthreads();
        #pragma unroll
        for (int kk = 0; kk < 64; kk += 32) {
            short8 af[4], bf[4];
            #pragma unroll
            for (int i = 0; i < 4; ++i)
                af[i] = *(const short8*)(As + (wm + i * 16 + mr) * 64 + kk + quad * 8);
            #pragma unroll
            for (int j = 0; j < 4; ++j)
                bf[j] = *(const short8*)(Bs + (wn + j * 16 + mr) * 64 + kk + quad * 8);
            #pragma unroll
            for (int i = 0; i < 4; ++i)
                #pragma unroll
                for (int j = 0; j < 4; ++j)
                    acc[i][j] = __builtin_amdgcn_mfma_f32_16x16x32_bf16(af[i], bf[j], acc[i][j], 0, 0, 0);
        }
    }
    #pragma unroll
    for (int j = 0; j < 4; ++j) {
        int col = n0 + wn + j * 16 + mr;
        float bs = bias[col];
        #pragma unroll
        for (int i = 0; i < 4; ++i) {
            int row = m0 + wm + i * 16 + quad * 4;
            #pragma unroll
            for (int ii = 0; ii < 4; ++ii)
                C[(size_t)(row + ii) * E_ + col] = f2bf_rne(acc[i][j][ii] + bs);
        }
    }
}

// ---------------- fc1 over all steps, LDS-staged: 128x128 tile, K=512 ----------------
__global__ void __launch_bounds__(256)
fc1tile_kernel(const unsigned short* __restrict__ Hall,  // [3136][512] (+OOB slack)
               const unsigned short* __restrict__ W,     // [10000][512] (+OOB slack)
               const float* __restrict__ bias,
               float* __restrict__ preds, const int* __restrict__ lens)
{
    __shared__ unsigned short As[128 * 64];
    __shared__ unsigned short Bs[128 * 64];
    int wv = threadIdx.x >> 6, lane = threadIdx.x & 63;
    int mr = lane & 15, quad = lane >> 4;
    int m0 = blockIdx.y * 128;
    int n0 = blockIdx.x * 128;
    int wm = (wv & 1) * 64, wn = (wv >> 1) * 64;
    int srow = wv * 32;
    int lrow = lane >> 3;
    int lcol = (lane & 7) * 8;
    floatx4 acc[4][4] = {};
    for (int k0 = 0; k0 < H_; k0 += 64) {
        __syncthreads();
        #pragma unroll
        for (int i = 0; i < 4; ++i) {
            int r = srow + i * 8;
            __builtin_amdgcn_global_load_lds(
                (gptr_t)(Hall + (size_t)(m0 + r + lrow) * H_ + k0 + lcol),
                (lptr_t)(As + r * 64), 16, 0, 0);
            __builtin_amdgcn_global_load_lds(
                (gptr_t)(W + (size_t)(n0 + r + lrow) * H_ + k0 + lcol),
                (lptr_t)(Bs + r * 64), 16, 0, 0);
        }
        __syncthreads();
        #pragma unroll
        for (int kk = 0; kk < 64; kk += 32) {
            short8 af[4], bf[4];
            #pragma unroll
            for (int i = 0; i < 4; ++i)
                af[i] = *(const short8*)(As + (wm + i * 16 + mr) * 64 + kk + quad * 8);
            #pragma unroll
            for (int j = 0; j < 4; ++j)
                bf[j] = *(const short8*)(Bs + (wn + j * 16 + mr) * 64 + kk + quad * 8);
            #pragma unroll
            for (int i = 0; i < 4; ++i)
                #pragma unroll
                for (int j = 0; j < 4; ++j)
                    acc[i][j] = __builtin_amdgcn_mfma_f32_16x16x32_bf16(af[i], bf[j], acc[i][j], 0, 0, 0);
        }
    }
    #pragma unroll
    for (int j = 0; j < 4; ++j) {
        int col = n0 + wn + j * 16 + mr;
        float bs = bias[min(col, V_ - 1)];
        #pragma unroll
        for (int i = 0; i < 4; ++i) {
            int row = m0 + wm + i * 16 + quad * 4;
            #pragma unroll
            for (int ii = 0; ii < 4; ++ii) {
                int r = row + ii;
                if (r < TMAX_ * B_ && col < V_) {
                    int t = r >> 6, b = r & 63;
                    float v = (lens[b] > t) ? (acc[i][j][ii] + bs) : 0.f;
                    preds[((size_t)b * TCAP_ + t) * V_ + col] = v;
                }
            }
        }
    }
}

// ---------------- skinny MFMA GEMM (used once for h0) ----------------
template<int KC>
__global__ void __launch_bounds__(256)
mfma_gemm64(const unsigned short* __restrict__ A, int ld,
            const unsigned short* __restrict__ W,
            const float* __restrict__ bias,
            float* __restrict__ C, unsigned short* __restrict__ Cbf, int ldc)
{
    int wv = threadIdx.x >> 6, lane = threadIdx.x & 63;
    int mr = lane & 15, quad = lane >> 4;
    int m0 = wv * 16;
    int n0 = blockIdx.x * 16;
    const unsigned short* pa = A + (size_t)(m0 + mr) * ld + quad * 8;
    const unsigned short* pb = W + (size_t)(n0 + mr) * ld + quad * 8;
    floatx4 acc = {0.f, 0.f, 0.f, 0.f};
    #pragma unroll 16
    for (int k0 = 0; k0 < KC; k0 += 32) {
        short8 a = *(const short8*)(const void*)(pa + k0);
        short8 b = *(const short8*)(const void*)(pb + k0);
        acc = __builtin_amdgcn_mfma_f32_16x16x32_bf16(a, b, acc, 0, 0, 0);
    }
    int col = n0 + mr;
    float bs = bias ? bias[col] : 0.f;
    #pragma unroll
    for (int i = 0; i < 4; ++i) {
        int row = m0 + quad * 4 + i;
        float v = acc[i] + bs;
        C[(size_t)row * ldc + col] = v;
        if (Cbf) Cbf[(size_t)row * ldc + col] = f2bf_rne(v);
    }
}

// ---------------- persistent fused recurrent loop ----------------
// 1024 blocks x 256 threads (4 blocks/CU: VGPR<=128, LDS 21.5KB). 4 phases/step:
//   A: h3 projections (352 blocks)   B: lam (64b x 16 p-groups)
//   C: softmax+z+gate+emb (64b x 16 col-chunks)   D: GRU (128 blocks)
__global__ void __launch_bounds__(256, 4)
loop_kernel(unsigned short* __restrict__ hbf,
            const unsigned short* __restrict__ whbf, const float* __restrict__ Wh_b,
            const unsigned short* __restrict__ fbbf, const float* __restrict__ fb_b,
            const unsigned short* __restrict__ ghhbf, const float* __restrict__ ghh_b,
            float* __restrict__ hwh, float* __restrict__ hf, float* __restrict__ gh,
            const unsigned short* __restrict__ xwx,
            const float* __restrict__ Vw, const float* __restrict__ Vb,
            float* __restrict__ lam,
            const unsigned short* __restrict__ fbf,
            const float* __restrict__ embed_w,
            const int* __restrict__ captions, const int* __restrict__ lens,
            unsigned short* __restrict__ inpbf,
            float* __restrict__ alphas,
            const unsigned short* __restrict__ wihbf, const float* __restrict__ b_ih,
            const float* __restrict__ h0,
            unsigned short* __restrict__ Hall,
            unsigned int* __restrict__ flags, unsigned int* __restrict__ go)
{
    __shared__ float smem[5376];   // 21 KiB: [0,3328) per-phase scratch, [3328,5376) = Vw
    float* sv = smem + 3328;
    const int bid = blockIdx.x;
    const int tid = threadIdx.x;
    const int wv = tid >> 6, lane = tid & 63;
    const int mr = lane & 15, quad = lane >> 4;
    unsigned int ep = 0;

    // Stage Vw once (immutable across steps); first phase-B __syncthreads orders it.
    {
        const float4* vs = (const float4*)Vw;
        ((float4*)sv)[tid]       = vs[tid];
        ((float4*)sv)[tid + 256] = vs[tid + 256];
    }

    // h state lives in a register of its owning phase-D thread (persistent blocks).
    float hreg = 0.f;
    if (bid < 128) {
        int row = tid >> 4, col = tid & 15;
        int b = (bid >> 5) * 16 + row, j = (bid & 31) * 16 + col;
        hreg = h0[(size_t)b * H_ + j];
    }

    for (int t = 0; t < TMAX_; ++t) {
        // ---------- phase A: hwh / hf / gh = h @ {Wh, f_beta, W_hh}^T ----------
        if (bid < 352) {
            const unsigned short* W; const float* bias; float* C; int n0; int ldc;
            if (bid < 128)      { W = whbf;  bias = Wh_b;  C = hwh; n0 = bid * 16;         ldc = E_; }
            else if (bid < 256) { W = fbbf;  bias = fb_b;  C = hf;  n0 = (bid - 128) * 16; ldc = E_; }
            else                { W = ghhbf; bias = ghh_b; C = gh;  n0 = (bid - 256) * 16; ldc = G3_; }
            int m0 = wv * 16;
            const unsigned short* pa = hbf + (size_t)(m0 + mr) * H_ + quad * 8;
            const unsigned short* pb = W + (size_t)(n0 + mr) * H_ + quad * 8;
            u32x4 av[8];
            floatx4 acc0 = {0.f, 0.f, 0.f, 0.f};
            floatx4 acc1 = {0.f, 0.f, 0.f, 0.f};
            GLD16(av[0], pa, 0);    GLD16(av[1], pa, 64);
            GLD16(av[2], pa, 128);  GLD16(av[3], pa, 192);
            GLD16(av[4], pa, 256);  GLD16(av[5], pa, 320);
            GLD16(av[6], pa, 384);  GLD16(av[7], pa, 448);
            asm volatile("s_waitcnt vmcnt(0)"
                : "+v"(av[0]), "+v"(av[1]), "+v"(av[2]), "+v"(av[3]),
                  "+v"(av[4]), "+v"(av[5]), "+v"(av[6]), "+v"(av[7]) :: "memory");
            __builtin_amdgcn_sched_barrier(0);
            #pragma unroll
            for (int i = 0; i < 8; i += 2) {
                short8 b0 = *(const short8*)(const void*)(pb + i * 32);
                short8 b1 = *(const short8*)(const void*)(pb + i * 32 + 32);
                acc0 = __builtin_amdgcn_mfma_f32_16x16x32_bf16(cvt8(av[i]),     b0, acc0, 0, 0, 0);
                acc1 = __builtin_amdgcn_mfma_f32_16x16x32_bf16(cvt8(av[i + 1]), b1, acc1, 0, 0, 0);
            }
            GLD16(av[0], pa, 512);  GLD16(av[1], pa, 576);
            GLD16(av[2], pa, 640);  GLD16(av[3], pa, 704);
            GLD16(av[4], pa, 768);  GLD16(av[5], pa, 832);
            GLD16(av[6], pa, 896);  GLD16(av[7], pa, 960);
            asm volatile("s_waitcnt vmcnt(0)"
                : "+v"(av[0]), "+v"(av[1]), "+v"(av[2]), "+v"(av[3]),
                  "+v"(av[4]), "+v"(av[5]), "+v"(av[6]), "+v"(av[7]) :: "memory");
            __builtin_amdgcn_sched_barrier(0);
            #pragma unroll
            for (int i = 0; i < 8; i += 2) {
                short8 b0 = *(const short8*)(const void*)(pb + 256 + i * 32);
                short8 b1 = *(const short8*)(const void*)(pb + 256 + i * 32 + 32);
                acc0 = __builtin_amdgcn_mfma_f32_16x16x32_bf16(cvt8(av[i]),     b0, acc0, 0, 0, 0);
                acc1 = __builtin_amdgcn_mfma_f32_16x16x32_bf16(cvt8(av[i + 1]), b1, acc1, 0, 0, 0);
            }
            floatx4 acc = acc0 + acc1;
            int col = n0 + mr;
            float bs = bias[col];
            #pragma unroll
            for (int i = 0; i < 4; ++i)
                stf(&C[(size_t)(m0 + quad * 4 + i) * ldc + col], acc[i] + bs);
        }
        gbar(flags, go, ++ep);

        // ---------- phase B: lam[b,p] = sum_e tanh(xwx + hwh)*Vw + Vb ----------
        {
            int b = bid >> 4, q = bid & 15;
            float* sh = smem;          // hwh[b], 2048 f32
            const float* hsrc = hwh + (size_t)b * E_;
            u32x4 hv0, hv1;
            GLD16(hv0, hsrc + tid * 4, 0);
            GLD16(hv1, hsrc + 1024 + tid * 4, 0);
            asm volatile("s_waitcnt vmcnt(0)" : "+v"(hv0), "+v"(hv1) :: "memory");
            __builtin_amdgcn_sched_barrier(0);
            ((u32x4*)sh)[tid]       = hv0;
            ((u32x4*)sh)[tid + 256] = hv1;
            __syncthreads();
            float vb0 = Vb[0];
            #pragma unroll
            for (int i = 0; i < 4; ++i) {
                int pl = wv + i * 4;
                int p = q + pl * 16;
                if (pl < 13 && p < P_) {
                    const unsigned short* px = xwx + ((size_t)b * P_ + p) * E_;
                    float acc = 0.f;
                    #pragma unroll
                    for (int it = 0; it < 4; ++it) {
                        int e = it * 512 + lane * 8;
                        u32x4 u = *(const u32x4*)(const void*)(px + e);
                        float4 h0v = *(const float4*)(sh + e);
                        float4 h1v = *(const float4*)(sh + e + 4);
                        float4 v0 = *(const float4*)(sv + e);
                        float4 v1 = *(const float4*)(sv + e + 4);
                        acc = fmaf(fast_tanh(bf2f(u[0] & 0xffffu) + h0v.x), v0.x, acc);
                        acc = fmaf(fast_tanh(bf2f(u[0] >> 16)     + h0v.y), v0.y, acc);
                        acc = fmaf(fast_tanh(bf2f(u[1] & 0xffffu) + h0v.z), v0.z, acc);
                        acc = fmaf(fast_tanh(bf2f(u[1] >> 16)     + h0v.w), v0.w, acc);
                        acc = fmaf(fast_tanh(bf2f(u[2] & 0xffffu) + h1v.x), v1.x, acc);
                        acc = fmaf(fast_tanh(bf2f(u[2] >> 16)     + h1v.y), v1.y, acc);
                        acc = fmaf(fast_tanh(bf2f(u[3] & 0xffffu) + h1v.z), v1.z, acc);
                        acc = fmaf(fast_tanh(bf2f(u[3] >> 16)     + h1v.w), v1.w, acc);
                    }
                    #pragma unroll
                    for (int off = 32; off > 0; off >>= 1) acc += __shfl_down(acc, off);
                    if (lane == 0) stf(&lam[b * P_ + p], acc + vb0);
                }
            }
        }
        gbar(flags, go, ++ep);

        // ---------- phase C: softmax + z + gate + emb -> inpbf, alphas ----------
        {
            int b = bid >> 4, c = bid & 15;
            int e0 = c * 128;
            float* sa = smem;          // 256: unnormalized exp
            float* sr = smem + 256;    // 8:   wave partials
            float* ps = smem + 512;    // 1024: z partials [8][128]
            float x = (tid < P_) ? ldf(&lam[b * P_ + tid]) : -1e30f;
            float mxl = x;
            #pragma unroll
            for (int off = 32; off > 0; off >>= 1) mxl = fmaxf(mxl, __shfl_xor(mxl, off));
            if (lane == 0) sr[wv] = mxl;
            __syncthreads();
            float mx = fmaxf(fmaxf(sr[0], sr[1]), fmaxf(sr[2], sr[3]));
            float ex = (tid < P_) ? __expf(x - mx) : 0.f;
            sa[tid] = ex;
            float sml = ex;
            #pragma unroll
            for (int off = 32; off > 0; off >>= 1) sml += __shfl_xor(sml, off);
            if (lane == 0) sr[4 + wv] = sml;
            __syncthreads();
            float inv = 1.f / (sr[4] + sr[5] + sr[6] + sr[7]);
            if (c == 0 && tid < P_)
                alphas[(size_t)b * TCAP_ * P_ + (size_t)t * P_ + tid] = (lens[b] > t) ? ex * inv : 0.f;
            if (c == 1) {
                int cap = captions[b * TCAP_ + t];
                float2 v = *(const float2*)(embed_w + (size_t)cap * EMB_ + tid * 2);
                stu((u32*)(inpbf + (size_t)b * KI_ + E_) + tid,
                    (u32)f2bf_rne(v.x) | ((u32)f2bf_rne(v.y) << 16));
            }
            // z over 128 cols: 8 row-groups x 32 col-threads, 8B/lane loads
            int rg = tid >> 5;            // 0..7
            int cl = (tid & 31) * 4;      // 0..124
            const unsigned short* fp = fbf + ((size_t)b * P_ + rg) * E_ + e0 + cl;
            float a0 = 0.f, a1 = 0.f, a2 = 0.f, a3 = 0.f;
            for (int p = rg; p < P_; p += 8) {
                u32x2 u = *(const u32x2*)(const void*)fp;
                fp += (size_t)8 * E_;
                float wgt = sa[p];
                a0 = fmaf(wgt, bf2f(u[0] & 0xffffu), a0);
                a1 = fmaf(wgt, bf2f(u[0] >> 16),     a1);
                a2 = fmaf(wgt, bf2f(u[1] & 0xffffu), a2);
                a3 = fmaf(wgt, bf2f(u[1] >> 16),     a3);
            }
            float* pw = ps + rg * 128 + cl;
            pw[0] = a0; pw[1] = a1; pw[2] = a2; pw[3] = a3;
            __syncthreads();
            if (tid < 64) {
                int col = tid * 2;
                float z0 = 0.f, z1 = 0.f;
                #pragma unroll
                for (int r8 = 0; r8 < 8; ++r8) {
                    z0 += ps[r8 * 128 + col];
                    z1 += ps[r8 * 128 + col + 1];
                }
                z0 *= inv; z1 *= inv;
                float g0 = ldf(hf + (size_t)b * E_ + e0 + col);
                float g1 = ldf(hf + (size_t)b * E_ + e0 + col + 1);
                stu((u32*)(inpbf + (size_t)b * KI_ + e0) + tid,
                    (u32)f2bf_rne(fast_sig(g0) * z0) | ((u32)f2bf_rne(fast_sig(g1) * z1) << 16));
            }
        }
        gbar(flags, go, ++ep);

        // ---------- phase D: gi GEMM + GRU combine -> hreg, hbf, Hall ----------
        if (bid < 128) {
            float (*red)[3][16][17] = (float (*)[3][16][17])smem;  // 13 KiB
            int j0 = (bid & 31) * 16;
            int m0 = (bid >> 5) * 16;
            int koff = wv * 640;
            const unsigned short* pa  = inpbf + (size_t)(m0 + mr) * KI_ + koff + quad * 8;
            const unsigned short* pb0 = wihbf + (size_t)(j0 + mr) * KI_ + koff + quad * 8;
            const unsigned short* pb1 = pb0 + (size_t)512 * KI_;
            const unsigned short* pb2 = pb0 + (size_t)1024 * KI_;
            floatx4 ar = {0.f,0.f,0.f,0.f}, az = {0.f,0.f,0.f,0.f}, an = {0.f,0.f,0.f,0.f};
            u32x4 av[10];
            GLD16(av[0], pa, 0);    GLD16(av[1], pa, 64);
            GLD16(av[2], pa, 128);  GLD16(av[3], pa, 192);
            GLD16(av[4], pa, 256);  GLD16(av[5], pa, 320);
            GLD16(av[6], pa, 384);  GLD16(av[7], pa, 448);
            GLD16(av[8], pa, 512);  GLD16(av[9], pa, 576);
            asm volatile("s_waitcnt vmcnt(0)"
                : "+v"(av[0]), "+v"(av[1]), "+v"(av[2]), "+v"(av[3]), "+v"(av[4]),
                  "+v"(av[5]), "+v"(av[6]), "+v"(av[7]), "+v"(av[8]), "+v"(av[9])
                :: "memory");
            __builtin_amdgcn_sched_barrier(0);
            #pragma unroll
            for (int k = 0; k < 10; ++k) {
                short8 a  = cvt8(av[k]);
                short8 br = *(const short8*)(const void*)(pb0 + k * 32);
                short8 bz = *(const short8*)(const void*)(pb1 + k * 32);
                short8 bn = *(const short8*)(const void*)(pb2 + k * 32);
                ar = __builtin_amdgcn_mfma_f32_16x16x32_bf16(a, br, ar, 0, 0, 0);
                az = __builtin_amdgcn_mfma_f32_16x16x32_bf16(a, bz, az, 0, 0, 0);
                an = __builtin_amdgcn_mfma_f32_16x16x32_bf16(a, bn, an, 0, 0, 0);
            }
            GLD16(av[0], pa, 640);  GLD16(av[1], pa, 704);
            GLD16(av[2], pa, 768);  GLD16(av[3], pa, 832);
            GLD16(av[4], pa, 896);  GLD16(av[5], pa, 960);
            GLD16(av[6], pa, 1024); GLD16(av[7], pa, 1088);
            GLD16(av[8], pa, 1152); GLD16(av[9], pa, 1216);
            asm volatile("s_waitcnt vmcnt(0)"
                : "+v"(av[0]), "+v"(av[1]), "+v"(av[2]), "+v"(av[3]), "+v"(av[4]),
                  "+v"(av[5]), "+v"(av[6]), "+v"(av[7]), "+v"(av[8]), "+v"(av[9])
                :: "memory");
            __builtin_amdgcn_sched_barrier(0);
            #pragma unroll
            for (int k = 0; k < 10; ++k) {
                short8 a  = cvt8(av[k]);
                short8 br = *(const short8*)(const void*)(pb0 + 320 + k * 32);
                short8 bz = *(const short8*)(const void*)(pb1 + 320 + k * 32);
                short8 bn = *(const short8*)(const void*)(pb2 + 320 + k * 32);
                ar = __builtin_amdgcn_mfma_f32_16x16x32_bf16(a, br, ar, 0, 0, 0);
                az = __builtin_amdgcn_mfma_f32_16x16x32_bf16(a, bz, az, 0, 0, 0);
                an = __builtin_amdgcn_mfma_f32_16x16x32_bf16(a, bn, an, 0, 0, 0);
            }
            #pragma unroll
            for (int i = 0; i < 4; ++i) {
                red[wv][0][quad * 4 + i][mr] = ar[i];
                red[wv][1][quad * 4 + i][mr] = az[i];
                red[wv][2][quad * 4 + i][mr] = an[i];
            }
            __syncthreads();
            int row = tid >> 4, col = tid & 15;
            int b = m0 + row, j = j0 + col;
            float ir = red[0][0][row][col] + red[1][0][row][col] + red[2][0][row][col] + red[3][0][row][col] + b_ih[j];
            float iz = red[0][1][row][col] + red[1][1][row][col] + red[2][1][row][col] + red[3][1][row][col] + b_ih[512 + j];
            float in_= red[0][2][row][col] + red[1][2][row][col] + red[2][2][row][col] + red[3][2][row][col] + b_ih[1024 + j];
            float hr = ldf(&gh[(size_t)b * G3_ + j]);
            float hz = ldf(&gh[(size_t)b * G3_ + 512 + j]);
            float hn = ldf(&gh[(size_t)b * G3_ + 1024 + j]);
            float r  = fast_sig(ir + hr);
            float zg = fast_sig(iz + hz);
            float n  = fast_tanh(in_ + r * hn);
            float hv = (1.f - zg) * n + zg * hreg;
            float ho = (lens[b] > t) ? hv : hreg;
            hreg = ho;
            unsigned short hob = f2bf_rne(ho);
            u32 nb = (u32)(unsigned short)__shfl_down((int)hob, 1);
            if ((tid & 1) == 0)
                stu((u32*)hbf + ((size_t)b * H_ + j) / 2, (u32)hob | (nb << 16));
            Hall[((size_t)t * B_ + b) * H_ + j] = hob;
        }
        gbar(flags, go, ++ep);
    }
}

extern "C" void kernel_launch(void* const* d_in, const int* in_sizes, int n_in,
                              void* d_out, int out_size, void* d_ws, size_t ws_size,
                              hipStream_t stream)
{
    const float* features  = (const float*)d_in[0];
    const int*   captions  = (const int*)d_in[1];
    const int*   lengths   = (const int*)d_in[2];
    const float* Wx_w      = (const float*)d_in[3];
    const float* Wx_b      = (const float*)d_in[4];
    const float* Wh_w      = (const float*)d_in[5];
    const float* Wh_b      = (const float*)d_in[6];
    const float* V_w       = (const float*)d_in[7];
    const float* V_b       = (const float*)d_in[8];
    const float* init_h_w  = (const float*)d_in[9];
    const float* init_h_b  = (const float*)d_in[10];
    const float* f_beta_w  = (const float*)d_in[11];
    const float* f_beta_b  = (const float*)d_in[12];
    const float* embed_w   = (const float*)d_in[13];
    const float* gru_w_ih  = (const float*)d_in[14];
    const float* gru_b_ih  = (const float*)d_in[15];
    const float* gru_w_hh  = (const float*)d_in[16];
    const float* gru_b_hh  = (const float*)d_in[17];
    const float* fc1_w     = (const float*)d_in[18];
    const float* fc1_b     = (const float*)d_in[19];

    float* preds  = (float*)d_out;
    float* alphas = preds + (size_t)B_ * TCAP_ * V_;
    float* dec    = alphas + (size_t)B_ * TCAP_ * P_;

    char* w = (char*)d_ws;
    unsigned short* fbf     = (unsigned short*)w; w += (size_t)12544 * 2048 * 2;
    unsigned short* xwx     = (unsigned short*)w; w += (size_t)12544 * 2048 * 2;
    unsigned short* wxbf    = (unsigned short*)w; w += (size_t)2048 * 2048 * 2;
    unsigned short* whbf    = (unsigned short*)w; w += (size_t)2048 * 512 * 2;
    unsigned short* fbbf    = (unsigned short*)w; w += (size_t)2048 * 512 * 2;
    unsigned short* ghhbf   = (unsigned short*)w; w += (size_t)1536 * 512 * 2;
    unsigned short* wihbf   = (unsigned short*)w; w += (size_t)1536 * 2560 * 2;
    unsigned short* fc1bf   = (unsigned short*)w; w += (size_t)10112 * 512 * 2;  // +slack for OOB tile reads
    unsigned short* ihwbf   = (unsigned short*)w; w += (size_t)512 * 2048 * 2;
    unsigned short* fmeanbf = (unsigned short*)w; w += (size_t)64 * 2048 * 2;
    unsigned short* hbf     = (unsigned short*)w; w += (size_t)64 * 512 * 2;
    unsigned short* inpbf   = (unsigned short*)w; w += (size_t)64 * KI_ * 2;
    unsigned short* Hall    = (unsigned short*)w; w += (size_t)3200 * 512 * 2;   // +slack rows
    float* h   = (float*)w; w += (size_t)64 * 512 * 4;
    float* hwh = (float*)w; w += (size_t)64 * 2048 * 4;
    float* hf  = (float*)w; w += (size_t)64 * 2048 * 4;
    float* gh  = (float*)w; w += (size_t)64 * 1536 * 4;
    float* lam = (float*)w; w += (size_t)64 * 196 * 4;
    unsigned int* flags = (unsigned int*)w; w += (size_t)NBLK_ * FSTRIDE * 4;
    unsigned int* go    = (unsigned int*)w; w += (size_t)NGO_ * FSTRIDE * 4;

    init_out_kernel<<<2500, 256, 0, stream>>>(preds, alphas, dec, lengths, flags, go);

    f2bf_kernel<<<12544, 256, 0, stream>>>(features, fbf, 12544 * 2048 / 8);
    f2bf_kernel<<<2048, 256, 0, stream>>>(Wx_w, wxbf, 2048 * 2048 / 8);
    f2bf_kernel<<<512, 256, 0, stream>>>(Wh_w, whbf, 2048 * 512 / 8);
    f2bf_kernel<<<512, 256, 0, stream>>>(f_beta_w, fbbf, 2048 * 512 / 8);
    f2bf_kernel<<<384, 256, 0, stream>>>(gru_w_hh, ghhbf, 1536 * 512 / 8);
    f2bf_kernel<<<1920, 256, 0, stream>>>(gru_w_ih, wihbf, 1536 * 2560 / 8);
    f2bf_kernel<<<2500, 256, 0, stream>>>(fc1_w, fc1bf, 10000 * 512 / 8);
    f2bf_kernel<<<512, 256, 0, stream>>>(init_h_w, ihwbf, 512 * 2048 / 8);

    mean_kernel<<<512, 256, 0, stream>>>(features, fmeanbf);
    mfma_gemm64<2048><<<32, 256, 0, stream>>>(fmeanbf, 2048, ihwbf, init_h_b, h, hbf, 512);
    mfma_xwx_kernel<<<dim3(16, 98), 256, 0, stream>>>(fbf, wxbf, Wx_b, xwx);

    loop_kernel<<<NBLK_, 256, 0, stream>>>(hbf, whbf, Wh_b, fbbf, f_beta_b, ghhbf, gru_b_hh,
                                           hwh, hf, gh, xwx, V_w, V_b, lam, fbf, embed_w,
                                           captions, lengths, inpbf, alphas, wihbf, gru_b_ih,
                                           h, Hall, flags, go);

    fc1tile_kernel<<<dim3(79, 25), 256, 0, stream>>>(Hall, fc1bf, fc1_b, preds, lengths);
}

// Round 7
// 3603.459 us; speedup vs baseline: 1.1249x; 1.1249x over previous
//
#include <hip/hip_runtime.h>
#include <cstddef>

#define B_    64
#define P_    196
#define E_    2048
#define H_    512
#define EMB_  512
#define V_    10000
#define TCAP_ 50
#define TMAX_ 49
#define KI_   2560   // E_ + EMB_
#define G3_   1536   // 3*H_
#define NBLK_ 512    // persistent loop kernel grid (2 blocks/CU on 256 CUs)
#define FSTRIDE 32   // 128B spacing between barrier flag lines
#define NGO_  8
#define COLLECTOR_ (NBLK_ - 1)

typedef __attribute__((ext_vector_type(8))) short short8;
typedef __attribute__((ext_vector_type(4))) float floatx4;
typedef unsigned int u32;
typedef __attribute__((ext_vector_type(4))) unsigned int u32x4;
typedef const __attribute__((address_space(1))) u32* gptr_t;
typedef __attribute__((address_space(3))) u32* lptr_t;

__device__ __forceinline__ unsigned short f2bf_rne(float f) {
    unsigned int x = __float_as_uint(f);
    unsigned int r = (x + 0x7fffu + ((x >> 16) & 1u)) >> 16;
    return (unsigned short)r;
}
__device__ __forceinline__ float bf2f(unsigned int u16) {
    return __uint_as_float(u16 << 16);
}
__device__ __forceinline__ float fast_tanh(float x) {
    float a = fabsf(x);
    float e = __expf(2.0f * a);
    float r = 1.0f - 2.0f / (e + 1.0f);
    return (x < 0.0f) ? -r : r;
}
__device__ __forceinline__ float fast_sig(float x) {
    return 1.0f / (1.0f + __expf(-x));
}

// ---- agent-coherent (sc1) scalar accessors for cross-phase data ----
__device__ __forceinline__ float ldf(const float* p) {
    return __hip_atomic_load((float*)p, __ATOMIC_RELAXED, __HIP_MEMORY_SCOPE_AGENT);
}
__device__ __forceinline__ void stf(float* p, float v) {
    __hip_atomic_store(p, v, __ATOMIC_RELAXED, __HIP_MEMORY_SCOPE_AGENT);
}
__device__ __forceinline__ void stu(u32* p, u32 v) {
    __hip_atomic_store(p, v, __ATOMIC_RELAXED, __HIP_MEMORY_SCOPE_AGENT);
}
__device__ __forceinline__ short8 cvt8(u32x4 v) {
    union { u32x4 u; short8 s; } x; x.u = v; return x.s;
}

// Vectorized coherent load: global_load_dwordx4 with sc1.
#define GLD16(dst, base, OFF) \
    asm volatile("global_load_dwordx4 %0, %1, off offset:" #OFF " sc1" \
                 : "=v"(dst) : "v"(base) : "memory")

// Fence-free GLOBAL grid barrier (sc1 data path). Collector = block 511.
__device__ __forceinline__ void gbar(unsigned int* __restrict__ flags,
                                     unsigned int* __restrict__ go,
                                     unsigned int ep)
{
    asm volatile("s_waitcnt vmcnt(0)" ::: "memory");
    __syncthreads();
    if (blockIdx.x == COLLECTOR_) {
        int tid = threadIdx.x;
        for (int s = tid; s < NBLK_ - 1; s += 256) {
            while (__hip_atomic_load(&flags[s * FSTRIDE], __ATOMIC_RELAXED,
                                     __HIP_MEMORY_SCOPE_AGENT) < ep)
                __builtin_amdgcn_s_sleep(1);
        }
        __syncthreads();
        if (tid < NGO_)
            __hip_atomic_store(&go[tid * FSTRIDE], ep, __ATOMIC_RELAXED,
                               __HIP_MEMORY_SCOPE_AGENT);
    } else {
        if (threadIdx.x == 0) {
            __hip_atomic_store(&flags[blockIdx.x * FSTRIDE], ep, __ATOMIC_RELAXED,
                               __HIP_MEMORY_SCOPE_AGENT);
            while (__hip_atomic_load(&go[(blockIdx.x & (NGO_ - 1)) * FSTRIDE],
                                     __ATOMIC_RELAXED, __HIP_MEMORY_SCOPE_AGENT) < ep)
                __builtin_amdgcn_s_sleep(1);
        }
    }
    __syncthreads();
}

// GROUP barrier: all-to-all among the 8 blocks of one batch-group
// (blocks [bid&~7, bid&~7+8)). Own-flag store + 8 direct peer polls — one
// IF$ hop, no collector. Used only for the lam→softmax handoff.
__device__ __forceinline__ void groupbar(unsigned int* __restrict__ gflags,
                                         unsigned int gep)
{
    asm volatile("s_waitcnt vmcnt(0)" ::: "memory");
    __syncthreads();
    if (threadIdx.x == 0)
        __hip_atomic_store(&gflags[blockIdx.x * FSTRIDE], gep, __ATOMIC_RELAXED,
                           __HIP_MEMORY_SCOPE_AGENT);
    if (threadIdx.x < 8) {
        int peer = (blockIdx.x & ~7) + threadIdx.x;
        while (__hip_atomic_load(&gflags[peer * FSTRIDE], __ATOMIC_RELAXED,
                                 __HIP_MEMORY_SCOPE_AGENT) < gep)
            __builtin_amdgcn_s_sleep(1);
    }
    __syncthreads();
}

// ---------------- output init: zero t=49 slices, write dec, reset barriers ----------------
__global__ void init_out_kernel(float* __restrict__ preds, float* __restrict__ alphas,
                                float* __restrict__ dec, const int* __restrict__ lens,
                                unsigned int* __restrict__ flags, unsigned int* __restrict__ go,
                                unsigned int* __restrict__ gflags)
{
    int i = blockIdx.x * 256 + threadIdx.x;
    if (i < NBLK_ * FSTRIDE) { flags[i] = 0u; gflags[i] = 0u; }
    if (i < NGO_ * FSTRIDE) go[i] = 0u;
    if (i < B_ * V_) {
        int b = i / V_, v = i - b * V_;
        preds[((size_t)b * TCAP_ + TMAX_) * V_ + v] = 0.f;
    }
    if (i < B_ * P_) {
        int b = i / P_, p = i - b * P_;
        alphas[((size_t)b * TCAP_ + TMAX_) * P_ + p] = 0.f;
    }
    if (i < B_) dec[i] = (float)(lens[i] - 1);
}

// ---------------- f32 -> bf16 cast (8 elems/thread) ----------------
__global__ void f2bf_kernel(const float* __restrict__ src, unsigned short* __restrict__ dst, int n8)
{
    int i = blockIdx.x * 256 + threadIdx.x;
    if (i >= n8) return;
    float4 a = ((const float4*)src)[2 * i];
    float4 b = ((const float4*)src)[2 * i + 1];
    uint4 o;
    o.x = (unsigned)f2bf_rne(a.x) | ((unsigned)f2bf_rne(a.y) << 16);
    o.y = (unsigned)f2bf_rne(a.z) | ((unsigned)f2bf_rne(a.w) << 16);
    o.z = (unsigned)f2bf_rne(b.x) | ((unsigned)f2bf_rne(b.y) << 16);
    o.w = (unsigned)f2bf_rne(b.z) | ((unsigned)f2bf_rne(b.w) << 16);
    ((uint4*)dst)[i] = o;
}

// ---------------- mean over P, output bf16 (64 x 2048) ----------------
__global__ void mean_kernel(const float* __restrict__ f, unsigned short* __restrict__ out)
{
    int i = blockIdx.x * 256 + threadIdx.x;
    int b = i >> 11, e = i & 2047;
    const float* p = f + (size_t)b * P_ * E_ + e;
    float s = 0.f;
    #pragma unroll 4
    for (int k = 0; k < P_; ++k) s += p[(size_t)k * E_];
    out[i] = f2bf_rne(s * (1.0f / (float)P_));
}

// ---------------- xwx GEMM, LDS-staged: 128x128 tile, BK=64 ----------------
__global__ void __launch_bounds__(256)
mfma_xwx_kernel(const unsigned short* __restrict__ A,   // [12544][2048]
                const unsigned short* __restrict__ W,   // [2048][2048]
                const float* __restrict__ bias,
                unsigned short* __restrict__ C)         // [12544][2048] bf16
{
    __shared__ unsigned short As[128 * 64];
    __shared__ unsigned short Bs[128 * 64];
    int wv = threadIdx.x >> 6, lane = threadIdx.x & 63;
    int mr = lane & 15, quad = lane >> 4;
    int m0 = blockIdx.y * 128;
    int n0 = blockIdx.x * 128;
    int wm = (wv & 1) * 64, wn = (wv >> 1) * 64;
    int srow = wv * 32;
    int lrow = lane >> 3;
    int lcol = (lane & 7) * 8;
    floatx4 acc[4][4] = {};
    for (int k0 = 0; k0 < E_; k0 += 64) {
        __syncthreads();
        #pragma unroll
        for (int i = 0; i < 4; ++i) {
            int r = srow + i * 8;
            __builtin_amdgcn_global_load_lds(
                (gptr_t)(A + (size_t)(m0 + r + lrow) * E_ + k0 + lcol),
                (lptr_t)(As + r * 64), 16, 0, 0);
            __builtin_amdgcn_global_load_lds(
                (gptr_t)(W + (size_t)(n0 + r + lrow) * E_ + k0 + lcol),
                (lptr_t)(Bs + r * 64), 16, 0, 0);
        }
        __syncthreads();
        #pragma unroll
        for (int kk = 0; kk < 64; kk += 32) {
            short8 af[4], bf[4];
            #pragma unroll
            for (int i = 0; i < 4; ++i)
                af[i] = *(const short8*)(As + (wm + i * 16 + mr) * 64 + kk + quad * 8);
            #pragma unroll
            for (int j = 0; j < 4; ++j)
                bf[j] = *(const short8*)(Bs + (wn + j * 16 + mr) * 64 + kk + quad * 8);
            #pragma unroll
            for (int i = 0; i < 4; ++i)
                #pragma unroll
                for (int j = 0; j < 4; ++j)
                    acc[i][j] = __builtin_amdgcn_mfma_f32_16x16x32_bf16(af[i], bf[j], acc[i][j], 0, 0, 0);
        }
    }
    #pragma unroll
    for (int j = 0; j < 4; ++j) {
        int col = n0 + wn + j * 16 + mr;
        float bs = bias[col];
        #pragma unroll
        for (int i = 0; i < 4; ++i) {
            int row = m0 + wm + i * 16 + quad * 4;
            #pragma unroll
            for (int ii = 0; ii < 4; ++ii)
                C[(size_t)(row + ii) * E_ + col] = f2bf_rne(acc[i][j][ii] + bs);
        }
    }
}

// ---------------- fc1 over all steps, LDS-staged: 128x128 tile, K=512 ----------------
__global__ void __launch_bounds__(256)
fc1tile_kernel(const unsigned short* __restrict__ Hall,  // [3136][512] (+OOB slack)
               const unsigned short* __restrict__ W,     // [10000][512] (+OOB slack)
               const float* __restrict__ bias,
               float* __restrict__ preds, const int* __restrict__ lens)
{
    __shared__ unsigned short As[128 * 64];
    __shared__ unsigned short Bs[128 * 64];
    int wv = threadIdx.x >> 6, lane = threadIdx.x & 63;
    int mr = lane & 15, quad = lane >> 4;
    int m0 = blockIdx.y * 128;
    int n0 = blockIdx.x * 128;
    int wm = (wv & 1) * 64, wn = (wv >> 1) * 64;
    int srow = wv * 32;
    int lrow = lane >> 3;
    int lcol = (lane & 7) * 8;
    floatx4 acc[4][4] = {};
    for (int k0 = 0; k0 < H_; k0 += 64) {
        __syncthreads();
        #pragma unroll
        for (int i = 0; i < 4; ++i) {
            int r = srow + i * 8;
            __builtin_amdgcn_global_load_lds(
                (gptr_t)(Hall + (size_t)(m0 + r + lrow) * H_ + k0 + lcol),
                (lptr_t)(As + r * 64), 16, 0, 0);
            __builtin_amdgcn_global_load_lds(
                (gptr_t)(W + (size_t)(n0 + r + lrow) * H_ + k0 + lcol),
                (lptr_t)(Bs + r * 64), 16, 0, 0);
        }
        __syncthreads();
        #pragma unroll
        for (int kk = 0; kk < 64; kk += 32) {
            short8 af[4], bf[4];
            #pragma unroll
            for (int i = 0; i < 4; ++i)
                af[i] = *(const short8*)(As + (wm + i * 16 + mr) * 64 + kk + quad * 8);
            #pragma unroll
            for (int j = 0; j < 4; ++j)
                bf[j] = *(const short8*)(Bs + (wn + j * 16 + mr) * 64 + kk + quad * 8);
            #pragma unroll
            for (int i = 0; i < 4; ++i)
                #pragma unroll
                for (int j = 0; j < 4; ++j)
                    acc[i][j] = __builtin_amdgcn_mfma_f32_16x16x32_bf16(af[i], bf[j], acc[i][j], 0, 0, 0);
        }
    }
    #pragma unroll
    for (int j = 0; j < 4; ++j) {
        int col = n0 + wn + j * 16 + mr;
        float bs = bias[min(col, V_ - 1)];
        #pragma unroll
        for (int i = 0; i < 4; ++i) {
            int row = m0 + wm + i * 16 + quad * 4;
            #pragma unroll
            for (int ii = 0; ii < 4; ++ii) {
                int r = row + ii;
                if (r < TMAX_ * B_ && col < V_) {
                    int t = r >> 6, b = r & 63;
                    float v = (lens[b] > t) ? (acc[i][j][ii] + bs) : 0.f;
                    preds[((size_t)b * TCAP_ + t) * V_ + col] = v;
                }
            }
        }
    }
}

// ---------------- skinny MFMA GEMM (used once for h0) ----------------
template<int KC>
__global__ void __launch_bounds__(256)
mfma_gemm64(const unsigned short* __restrict__ A, int ld,
            const unsigned short* __restrict__ W,
            const float* __restrict__ bias,
            float* __restrict__ C, unsigned short* __restrict__ Cbf, int ldc)
{
    int wv = threadIdx.x >> 6, lane = threadIdx.x & 63;
    int mr = lane & 15, quad = lane >> 4;
    int m0 = wv * 16;
    int n0 = blockIdx.x * 16;
    const unsigned short* pa = A + (size_t)(m0 + mr) * ld + quad * 8;
    const unsigned short* pb = W + (size_t)(n0 + mr) * ld + quad * 8;
    floatx4 acc = {0.f, 0.f, 0.f, 0.f};
    #pragma unroll 16
    for (int k0 = 0; k0 < KC; k0 += 32) {
        short8 a = *(const short8*)(const void*)(pa + k0);
        short8 b = *(const short8*)(const void*)(pb + k0);
        acc = __builtin_amdgcn_mfma_f32_16x16x32_bf16(a, b, acc, 0, 0, 0);
    }
    int col = n0 + mr;
    float bs = bias ? bias[col] : 0.f;
    #pragma unroll
    for (int i = 0; i < 4; ++i) {
        int row = m0 + quad * 4 + i;
        float v = acc[i] + bs;
        C[(size_t)row * ldc + col] = v;
        if (Cbf) Cbf[(size_t)row * ldc + col] = f2bf_rne(v);
    }
}

// ---------------- persistent fused recurrent loop ----------------
// 512 blocks x 256 threads (2 blocks/CU). Per step: 3 GLOBAL barriers + 1
// group barrier:  A (352 blocks) | gbar | B-sub + groupbar + C-sub | gbar |
// D (128 blocks) | gbar.
__global__ void __launch_bounds__(256, 2)
loop_kernel(unsigned short* __restrict__ hbf,
            const unsigned short* __restrict__ whbf, const float* __restrict__ Wh_b,
            const unsigned short* __restrict__ fbbf, const float* __restrict__ fb_b,
            const unsigned short* __restrict__ ghhbf, const float* __restrict__ ghh_b,
            float* __restrict__ hwh, float* __restrict__ hf, float* __restrict__ gh,
            const unsigned short* __restrict__ xwx,
            const float* __restrict__ Vw, const float* __restrict__ Vb,
            float* __restrict__ lam,
            const unsigned short* __restrict__ fbf,
            const float* __restrict__ embed_w,
            const int* __restrict__ captions, const int* __restrict__ lens,
            unsigned short* __restrict__ inpbf,
            float* __restrict__ alphas,
            const unsigned short* __restrict__ wihbf, const float* __restrict__ b_ih,
            const float* __restrict__ h0,
            unsigned short* __restrict__ Hall,
            unsigned int* __restrict__ flags, unsigned int* __restrict__ go,
            unsigned int* __restrict__ gflags)
{
    __shared__ float smem[5376];   // 21 KiB: [0,3328) per-phase scratch, [3328,5376) = Vw
    float* sv = smem + 3328;
    const int bid = blockIdx.x;
    const int tid = threadIdx.x;
    const int wv = tid >> 6, lane = tid & 63;
    const int mr = lane & 15, quad = lane >> 4;
    unsigned int ep = 0;

    // Stage Vw once (immutable across steps); first B-sub __syncthreads orders it.
    {
        const float4* vs = (const float4*)Vw;
        ((float4*)sv)[tid]       = vs[tid];
        ((float4*)sv)[tid + 256] = vs[tid + 256];
    }

    // h state lives in a register of its owning phase-D thread (persistent blocks).
    float hreg = 0.f;
    if (bid < 128) {
        int row = tid >> 4, col = tid & 15;
        int b = (bid >> 5) * 16 + row, j = (bid & 31) * 16 + col;
        hreg = h0[(size_t)b * H_ + j];
    }

    for (int t = 0; t < TMAX_; ++t) {
        // ---------- phase A: hwh / hf / gh = h @ {Wh, f_beta, W_hh}^T ----------
        if (bid < 352) {
            const unsigned short* W; const float* bias; float* C; int n0; int ldc;
            if (bid < 128)      { W = whbf;  bias = Wh_b;  C = hwh; n0 = bid * 16;         ldc = E_; }
            else if (bid < 256) { W = fbbf;  bias = fb_b;  C = hf;  n0 = (bid - 128) * 16; ldc = E_; }
            else                { W = ghhbf; bias = ghh_b; C = gh;  n0 = (bid - 256) * 16; ldc = G3_; }
            int m0 = wv * 16;
            const unsigned short* pa = hbf + (size_t)(m0 + mr) * H_ + quad * 8;
            const unsigned short* pb = W + (size_t)(n0 + mr) * H_ + quad * 8;
            u32x4 av[16];
            GLD16(av[0],  pa, 0);    GLD16(av[1],  pa, 64);
            GLD16(av[2],  pa, 128);  GLD16(av[3],  pa, 192);
            GLD16(av[4],  pa, 256);  GLD16(av[5],  pa, 320);
            GLD16(av[6],  pa, 384);  GLD16(av[7],  pa, 448);
            GLD16(av[8],  pa, 512);  GLD16(av[9],  pa, 576);
            GLD16(av[10], pa, 640);  GLD16(av[11], pa, 704);
            GLD16(av[12], pa, 768);  GLD16(av[13], pa, 832);
            GLD16(av[14], pa, 896);  GLD16(av[15], pa, 960);
            asm volatile("s_waitcnt vmcnt(0)"
                : "+v"(av[0]), "+v"(av[1]), "+v"(av[2]),  "+v"(av[3]),
                  "+v"(av[4]), "+v"(av[5]), "+v"(av[6]),  "+v"(av[7]),
                  "+v"(av[8]), "+v"(av[9]), "+v"(av[10]), "+v"(av[11]),
                  "+v"(av[12]),"+v"(av[13]),"+v"(av[14]), "+v"(av[15])
                :: "memory");
            __builtin_amdgcn_sched_barrier(0);
            floatx4 acc0 = {0.f, 0.f, 0.f, 0.f};
            floatx4 acc1 = {0.f, 0.f, 0.f, 0.f};
            #pragma unroll
            for (int i = 0; i < 16; i += 2) {
                short8 b0 = *(const short8*)(const void*)(pb + i * 32);
                short8 b1 = *(const short8*)(const void*)(pb + i * 32 + 32);
                acc0 = __builtin_amdgcn_mfma_f32_16x16x32_bf16(cvt8(av[i]),     b0, acc0, 0, 0, 0);
                acc1 = __builtin_amdgcn_mfma_f32_16x16x32_bf16(cvt8(av[i + 1]), b1, acc1, 0, 0, 0);
            }
            floatx4 acc = acc0 + acc1;
            int col = n0 + mr;
            float bs = bias[col];
            #pragma unroll
            for (int i = 0; i < 4; ++i)
                stf(&C[(size_t)(m0 + quad * 4 + i) * ldc + col], acc[i] + bs);
        }
        gbar(flags, go, ++ep);

        // ---------- merged phase B+C (group-local lam handoff) ----------
        {
            int b = bid >> 3, q = bid & 7;
            // --- B-sub: lam[b,p] for p in q*25..q*25+24 ---
            float* sh = smem;          // hwh[b], 2048 f32
            const float* hsrc = hwh + (size_t)b * E_;
            u32x4 hv0, hv1;
            GLD16(hv0, hsrc + tid * 4, 0);
            GLD16(hv1, hsrc + 1024 + tid * 4, 0);
            asm volatile("s_waitcnt vmcnt(0)" : "+v"(hv0), "+v"(hv1) :: "memory");
            __builtin_amdgcn_sched_barrier(0);
            ((u32x4*)sh)[tid]       = hv0;
            ((u32x4*)sh)[tid + 256] = hv1;
            __syncthreads();
            float vb0 = Vb[0];
            #pragma unroll
            for (int i = 0; i < 7; ++i) {
                int pl = wv + i * 4;
                int p = q * 25 + pl;
                if (pl < 25 && p < P_) {
                    const unsigned short* px = xwx + ((size_t)b * P_ + p) * E_;
                    float acc = 0.f;
                    #pragma unroll
                    for (int it = 0; it < 4; ++it) {
                        int e = it * 512 + lane * 8;
                        u32x4 u = *(const u32x4*)(const void*)(px + e);
                        float4 h0v = *(const float4*)(sh + e);
                        float4 h1v = *(const float4*)(sh + e + 4);
                        float4 v0 = *(const float4*)(sv + e);
                        float4 v1 = *(const float4*)(sv + e + 4);
                        acc = fmaf(fast_tanh(bf2f(u[0] & 0xffffu) + h0v.x), v0.x, acc);
                        acc = fmaf(fast_tanh(bf2f(u[0] >> 16)     + h0v.y), v0.y, acc);
                        acc = fmaf(fast_tanh(bf2f(u[1] & 0xffffu) + h0v.z), v0.z, acc);
                        acc = fmaf(fast_tanh(bf2f(u[1] >> 16)     + h0v.w), v0.w, acc);
                        acc = fmaf(fast_tanh(bf2f(u[2] & 0xffffu) + h1v.x), v1.x, acc);
                        acc = fmaf(fast_tanh(bf2f(u[2] >> 16)     + h1v.y), v1.y, acc);
                        acc = fmaf(fast_tanh(bf2f(u[3] & 0xffffu) + h1v.z), v1.z, acc);
                        acc = fmaf(fast_tanh(bf2f(u[3] >> 16)     + h1v.w), v1.w, acc);
                    }
                    #pragma unroll
                    for (int off = 32; off > 0; off >>= 1) acc += __shfl_down(acc, off);
                    if (lane == 0) stf(&lam[b * P_ + p], acc + vb0);
                }
            }
            groupbar(gflags, (unsigned)(t + 1));
            // --- C-sub: softmax + z + gate + emb -> inpbf, alphas ---
            int c = q;
            int e0 = c * 256;
            float* sa = smem;          // 256: unnormalized exp
            float* sr = smem + 256;    // 8:   wave partials
            float* ps = smem + 512;    // 512: z partials
            float x = (tid < P_) ? ldf(&lam[b * P_ + tid]) : -1e30f;
            float mxl = x;
            #pragma unroll
            for (int off = 32; off > 0; off >>= 1) mxl = fmaxf(mxl, __shfl_xor(mxl, off));
            if (lane == 0) sr[wv] = mxl;
            __syncthreads();
            float mx = fmaxf(fmaxf(sr[0], sr[1]), fmaxf(sr[2], sr[3]));
            float ex = (tid < P_) ? __expf(x - mx) : 0.f;
            sa[tid] = ex;
            float sml = ex;
            #pragma unroll
            for (int off = 32; off > 0; off >>= 1) sml += __shfl_xor(sml, off);
            if (lane == 0) sr[4 + wv] = sml;
            __syncthreads();
            float inv = 1.f / (sr[4] + sr[5] + sr[6] + sr[7]);
            if (c == 0 && tid < P_)
                alphas[(size_t)b * TCAP_ * P_ + (size_t)t * P_ + tid] = (lens[b] > t) ? ex * inv : 0.f;
            if (c == 1) {
                int cap = captions[b * TCAP_ + t];
                float2 v = *(const float2*)(embed_w + (size_t)cap * EMB_ + tid * 2);
                stu((u32*)(inpbf + (size_t)b * KI_ + E_) + tid,
                    (u32)f2bf_rne(v.x) | ((u32)f2bf_rne(v.y) << 16));
            }
            int half = tid >> 7, li = tid & 127;
            const unsigned short* fp = fbf + ((size_t)b * P_ + half) * E_ + e0 + li * 2;
            float a0 = 0.f, a1 = 0.f;
            #pragma unroll 7
            for (int p = half; p < P_; p += 2) {
                u32 u = *(const u32*)(const void*)fp;
                fp += 2 * E_;
                float wgt = sa[p];
                a0 = fmaf(wgt, bf2f(u & 0xffffu), a0);
                a1 = fmaf(wgt, bf2f(u >> 16), a1);
            }
            ps[tid * 2]     = a0;
            ps[tid * 2 + 1] = a1;
            __syncthreads();
            if (tid < 128) {
                float z0 = (ps[tid * 2]     + ps[(tid + 128) * 2])     * inv;
                float z1 = (ps[tid * 2 + 1] + ps[(tid + 128) * 2 + 1]) * inv;
                float g0 = ldf(hf + (size_t)b * E_ + e0 + tid * 2);
                float g1 = ldf(hf + (size_t)b * E_ + e0 + tid * 2 + 1);
                stu((u32*)(inpbf + (size_t)b * KI_ + e0) + tid,
                    (u32)f2bf_rne(fast_sig(g0) * z0) | ((u32)f2bf_rne(fast_sig(g1) * z1) << 16));
            }
        }
        gbar(flags, go, ++ep);

        // ---------- phase D: gi GEMM + GRU combine -> hreg, hbf, Hall ----------
        if (bid < 128) {
            float (*red)[3][16][17] = (float (*)[3][16][17])smem;  // 13 KiB
            int j0 = (bid & 31) * 16;
            int m0 = (bid >> 5) * 16;
            int koff = wv * 640;
            const unsigned short* pa  = inpbf + (size_t)(m0 + mr) * KI_ + koff + quad * 8;
            const unsigned short* pb0 = wihbf + (size_t)(j0 + mr) * KI_ + koff + quad * 8;
            const unsigned short* pb1 = pb0 + (size_t)512 * KI_;
            const unsigned short* pb2 = pb0 + (size_t)1024 * KI_;
            u32x4 av[20];
            GLD16(av[0],  pa, 0);     GLD16(av[1],  pa, 64);
            GLD16(av[2],  pa, 128);   GLD16(av[3],  pa, 192);
            GLD16(av[4],  pa, 256);   GLD16(av[5],  pa, 320);
            GLD16(av[6],  pa, 384);   GLD16(av[7],  pa, 448);
            GLD16(av[8],  pa, 512);   GLD16(av[9],  pa, 576);
            GLD16(av[10], pa, 640);   GLD16(av[11], pa, 704);
            GLD16(av[12], pa, 768);   GLD16(av[13], pa, 832);
            GLD16(av[14], pa, 896);   GLD16(av[15], pa, 960);
            GLD16(av[16], pa, 1024);  GLD16(av[17], pa, 1088);
            GLD16(av[18], pa, 1152);  GLD16(av[19], pa, 1216);
            asm volatile("s_waitcnt vmcnt(0)"
                : "+v"(av[0]), "+v"(av[1]), "+v"(av[2]),  "+v"(av[3]),
                  "+v"(av[4]), "+v"(av[5]), "+v"(av[6]),  "+v"(av[7]),
                  "+v"(av[8]), "+v"(av[9]), "+v"(av[10]), "+v"(av[11]),
                  "+v"(av[12]),"+v"(av[13]),"+v"(av[14]), "+v"(av[15]),
                  "+v"(av[16]),"+v"(av[17]),"+v"(av[18]), "+v"(av[19])
                :: "memory");
            __builtin_amdgcn_sched_barrier(0);
            floatx4 ar = {0.f,0.f,0.f,0.f}, az = {0.f,0.f,0.f,0.f}, an = {0.f,0.f,0.f,0.f};
            #pragma unroll
            for (int k = 0; k < 20; ++k) {
                short8 a  = cvt8(av[k]);
                short8 br = *(const short8*)(const void*)(pb0 + k * 32);
                short8 bz = *(const short8*)(const void*)(pb1 + k * 32);
                short8 bn = *(const short8*)(const void*)(pb2 + k * 32);
                ar = __builtin_amdgcn_mfma_f32_16x16x32_bf16(a, br, ar, 0, 0, 0);
                az = __builtin_amdgcn_mfma_f32_16x16x32_bf16(a, bz, az, 0, 0, 0);
                an = __builtin_amdgcn_mfma_f32_16x16x32_bf16(a, bn, an, 0, 0, 0);
            }
            #pragma unroll
            for (int i = 0; i < 4; ++i) {
                red[wv][0][quad * 4 + i][mr] = ar[i];
                red[wv][1][quad * 4 + i][mr] = az[i];
                red[wv][2][quad * 4 + i][mr] = an[i];
            }
            __syncthreads();
            int row = tid >> 4, col = tid & 15;
            int b = m0 + row, j = j0 + col;
            float ir = red[0][0][row][col] + red[1][0][row][col] + red[2][0][row][col] + red[3][0][row][col] + b_ih[j];
            float iz = red[0][1][row][col] + red[1][1][row][col] + red[2][1][row][col] + red[3][1][row][col] + b_ih[512 + j];
            float in_= red[0][2][row][col] + red[1][2][row][col] + red[2][2][row][col] + red[3][2][row][col] + b_ih[1024 + j];
            float hr = ldf(&gh[(size_t)b * G3_ + j]);
            float hz = ldf(&gh[(size_t)b * G3_ + 512 + j]);
            float hn = ldf(&gh[(size_t)b * G3_ + 1024 + j]);
            float r  = fast_sig(ir + hr);
            float zg = fast_sig(iz + hz);
            float n  = fast_tanh(in_ + r * hn);
            float hv = (1.f - zg) * n + zg * hreg;
            float ho = (lens[b] > t) ? hv : hreg;
            hreg = ho;
            unsigned short hob = f2bf_rne(ho);
            u32 nb = (u32)(unsigned short)__shfl_down((int)hob, 1);
            if ((tid & 1) == 0)
                stu((u32*)hbf + ((size_t)b * H_ + j) / 2, (u32)hob | (nb << 16));
            Hall[((size_t)t * B_ + b) * H_ + j] = hob;
        }
        gbar(flags, go, ++ep);
    }
}

extern "C" void kernel_launch(void* const* d_in, const int* in_sizes, int n_in,
                              void* d_out, int out_size, void* d_ws, size_t ws_size,
                              hipStream_t stream)
{
    const float* features  = (const float*)d_in[0];
    const int*   captions  = (const int*)d_in[1];
    const int*   lengths   = (const int*)d_in[2];
    const float* Wx_w      = (const float*)d_in[3];
    const float* Wx_b      = (const float*)d_in[4];
    const float* Wh_w      = (const float*)d_in[5];
    const float* Wh_b      = (const float*)d_in[6];
    const float* V_w       = (const float*)d_in[7];
    const float* V_b       = (const float*)d_in[8];
    const float* init_h_w  = (const float*)d_in[9];
    const float* init_h_b  = (const float*)d_in[10];
    const float* f_beta_w  = (const float*)d_in[11];
    const float* f_beta_b  = (const float*)d_in[12];
    const float* embed_w   = (const float*)d_in[13];
    const float* gru_w_ih  = (const float*)d_in[14];
    const float* gru_b_ih  = (const float*)d_in[15];
    const float* gru_w_hh  = (const float*)d_in[16];
    const float* gru_b_hh  = (const float*)d_in[17];
    const float* fc1_w     = (const float*)d_in[18];
    const float* fc1_b     = (const float*)d_in[19];

    float* preds  = (float*)d_out;
    float* alphas = preds + (size_t)B_ * TCAP_ * V_;
    float* dec    = alphas + (size_t)B_ * TCAP_ * P_;

    char* w = (char*)d_ws;
    unsigned short* fbf     = (unsigned short*)w; w += (size_t)12544 * 2048 * 2;
    unsigned short* xwx     = (unsigned short*)w; w += (size_t)12544 * 2048 * 2;
    unsigned short* wxbf    = (unsigned short*)w; w += (size_t)2048 * 2048 * 2;
    unsigned short* whbf    = (unsigned short*)w; w += (size_t)2048 * 512 * 2;
    unsigned short* fbbf    = (unsigned short*)w; w += (size_t)2048 * 512 * 2;
    unsigned short* ghhbf   = (unsigned short*)w; w += (size_t)1536 * 512 * 2;
    unsigned short* wihbf   = (unsigned short*)w; w += (size_t)1536 * 2560 * 2;
    unsigned short* fc1bf   = (unsigned short*)w; w += (size_t)10112 * 512 * 2;  // +slack for OOB tile reads
    unsigned short* ihwbf   = (unsigned short*)w; w += (size_t)512 * 2048 * 2;
    unsigned short* fmeanbf = (unsigned short*)w; w += (size_t)64 * 2048 * 2;
    unsigned short* hbf     = (unsigned short*)w; w += (size_t)64 * 512 * 2;
    unsigned short* inpbf   = (unsigned short*)w; w += (size_t)64 * KI_ * 2;
    unsigned short* Hall    = (unsigned short*)w; w += (size_t)3200 * 512 * 2;   // +slack rows
    float* h   = (float*)w; w += (size_t)64 * 512 * 4;
    float* hwh = (float*)w; w += (size_t)64 * 2048 * 4;
    float* hf  = (float*)w; w += (size_t)64 * 2048 * 4;
    float* gh  = (float*)w; w += (size_t)64 * 1536 * 4;
    float* lam = (float*)w; w += (size_t)64 * 196 * 4;
    unsigned int* flags  = (unsigned int*)w; w += (size_t)NBLK_ * FSTRIDE * 4;
    unsigned int* go     = (unsigned int*)w; w += (size_t)NGO_ * FSTRIDE * 4;
    unsigned int* gflags = (unsigned int*)w; w += (size_t)NBLK_ * FSTRIDE * 4;

    init_out_kernel<<<2500, 256, 0, stream>>>(preds, alphas, dec, lengths, flags, go, gflags);

    f2bf_kernel<<<12544, 256, 0, stream>>>(features, fbf, 12544 * 2048 / 8);
    f2bf_kernel<<<2048, 256, 0, stream>>>(Wx_w, wxbf, 2048 * 2048 / 8);
    f2bf_kernel<<<512, 256, 0, stream>>>(Wh_w, whbf, 2048 * 512 / 8);
    f2bf_kernel<<<512, 256, 0, stream>>>(f_beta_w, fbbf, 2048 * 512 / 8);
    f2bf_kernel<<<384, 256, 0, stream>>>(gru_w_hh, ghhbf, 1536 * 512 / 8);
    f2bf_kernel<<<1920, 256, 0, stream>>>(gru_w_ih, wihbf, 1536 * 2560 / 8);
    f2bf_kernel<<<2500, 256, 0, stream>>>(fc1_w, fc1bf, 10000 * 512 / 8);
    f2bf_kernel<<<512, 256, 0, stream>>>(init_h_w, ihwbf, 512 * 2048 / 8);

    mean_kernel<<<512, 256, 0, stream>>>(features, fmeanbf);
    mfma_gemm64<2048><<<32, 256, 0, stream>>>(fmeanbf, 2048, ihwbf, init_h_b, h, hbf, 512);
    mfma_xwx_kernel<<<dim3(16, 98), 256, 0, stream>>>(fbf, wxbf, Wx_b, xwx);

    loop_kernel<<<NBLK_, 256, 0, stream>>>(hbf, whbf, Wh_b, fbbf, f_beta_b, ghhbf, gru_b_hh,
                                           hwh, hf, gh, xwx, V_w, V_b, lam, fbf, embed_w,
                                           captions, lengths, inpbf, alphas, wihbf, gru_b_ih,
                                           h, Hall, flags, go, gflags);

    fc1tile_kernel<<<dim3(79, 25), 256, 0, stream>>>(Hall, fc1bf, fc1_b, preds, lengths);
}

// Round 8
// 3478.849 us; speedup vs baseline: 1.1652x; 1.0358x over previous
//
#include <hip/hip_runtime.h>
#include <cstddef>

#define B_    64
#define P_    196
#define E_    2048
#define H_    512
#define EMB_  512
#define V_    10000
#define TCAP_ 50
#define TMAX_ 49
#define KI_   2560   // E_ + EMB_
#define G3_   1536   // 3*H_
#define NBLK_ 512    // persistent loop kernel grid (2 blocks/CU on 256 CUs)
#define FSTRIDE 32   // 128B spacing between barrier flag lines
#define NGO_  8
#define COLLECTOR_ (NBLK_ - 1)

typedef __attribute__((ext_vector_type(8))) short short8;
typedef __attribute__((ext_vector_type(4))) float floatx4;
typedef unsigned int u32;
typedef __attribute__((ext_vector_type(4))) unsigned int u32x4;
typedef const __attribute__((address_space(1))) u32* gptr_t;
typedef __attribute__((address_space(3))) u32* lptr_t;

__device__ __forceinline__ unsigned short f2bf_rne(float f) {
    unsigned int x = __float_as_uint(f);
    unsigned int r = (x + 0x7fffu + ((x >> 16) & 1u)) >> 16;
    return (unsigned short)r;
}
__device__ __forceinline__ float bf2f(unsigned int u16) {
    return __uint_as_float(u16 << 16);
}
__device__ __forceinline__ float fast_tanh(float x) {
    float a = fabsf(x);
    float e = __expf(2.0f * a);
    float r = 1.0f - 2.0f / (e + 1.0f);
    return (x < 0.0f) ? -r : r;
}
__device__ __forceinline__ float fast_sig(float x) {
    return 1.0f / (1.0f + __expf(-x));
}

// ---- agent-coherent (sc1) scalar accessors for cross-phase data ----
__device__ __forceinline__ float ldf(const float* p) {
    return __hip_atomic_load((float*)p, __ATOMIC_RELAXED, __HIP_MEMORY_SCOPE_AGENT);
}
__device__ __forceinline__ void stf(float* p, float v) {
    __hip_atomic_store(p, v, __ATOMIC_RELAXED, __HIP_MEMORY_SCOPE_AGENT);
}
__device__ __forceinline__ void stu(u32* p, u32 v) {
    __hip_atomic_store(p, v, __ATOMIC_RELAXED, __HIP_MEMORY_SCOPE_AGENT);
}
__device__ __forceinline__ short8 cvt8(u32x4 v) {
    union { u32x4 u; short8 s; } x; x.u = v; return x.s;
}

// Vectorized coherent load: global_load_dwordx4 with sc1 (cross-phase data).
#define GLD16(dst, base, OFF) \
    asm volatile("global_load_dwordx4 %0, %1, off offset:" #OFF " sc1" \
                 : "=v"(dst) : "v"(base) : "memory")
// Plain cached vectorized load (read-only streams: xwx, fbf).
#define GLDC16(dst, base, OFF) \
    asm volatile("global_load_dwordx4 %0, %1, off offset:" #OFF \
                 : "=v"(dst) : "v"(base) : "memory")

// Fence-free GLOBAL grid barrier (sc1 data path). Collector = block 511.
__device__ __forceinline__ void gbar(unsigned int* __restrict__ flags,
                                     unsigned int* __restrict__ go,
                                     unsigned int ep)
{
    asm volatile("s_waitcnt vmcnt(0)" ::: "memory");
    __syncthreads();
    if (blockIdx.x == COLLECTOR_) {
        int tid = threadIdx.x;
        for (int s = tid; s < NBLK_ - 1; s += 256) {
            while (__hip_atomic_load(&flags[s * FSTRIDE], __ATOMIC_RELAXED,
                                     __HIP_MEMORY_SCOPE_AGENT) < ep)
                __builtin_amdgcn_s_sleep(1);
        }
        __syncthreads();
        if (tid < NGO_)
            __hip_atomic_store(&go[tid * FSTRIDE], ep, __ATOMIC_RELAXED,
                               __HIP_MEMORY_SCOPE_AGENT);
    } else {
        if (threadIdx.x == 0) {
            __hip_atomic_store(&flags[blockIdx.x * FSTRIDE], ep, __ATOMIC_RELAXED,
                               __HIP_MEMORY_SCOPE_AGENT);
            while (__hip_atomic_load(&go[(blockIdx.x & (NGO_ - 1)) * FSTRIDE],
                                     __ATOMIC_RELAXED, __HIP_MEMORY_SCOPE_AGENT) < ep)
                __builtin_amdgcn_s_sleep(1);
        }
    }
    __syncthreads();
}

// GROUP barrier: all-to-all among the 8 blocks of one batch-group.
__device__ __forceinline__ void groupbar(unsigned int* __restrict__ gflags,
                                         unsigned int gep)
{
    asm volatile("s_waitcnt vmcnt(0)" ::: "memory");
    __syncthreads();
    if (threadIdx.x == 0)
        __hip_atomic_store(&gflags[blockIdx.x * FSTRIDE], gep, __ATOMIC_RELAXED,
                           __HIP_MEMORY_SCOPE_AGENT);
    if (threadIdx.x < 8) {
        int peer = (blockIdx.x & ~7) + threadIdx.x;
        while (__hip_atomic_load(&gflags[peer * FSTRIDE], __ATOMIC_RELAXED,
                                 __HIP_MEMORY_SCOPE_AGENT) < gep)
            __builtin_amdgcn_s_sleep(1);
    }
    __syncthreads();
}

// lam inner-row accumulate: 8 bf16 of xwx + hwh -> tanh -> *Vw
__device__ __forceinline__ float brow_acc(u32x4 u, const float* sh, const float* sv,
                                          int e, float acc)
{
    float4 h0v = *(const float4*)(sh + e);
    float4 h1v = *(const float4*)(sh + e + 4);
    float4 v0 = *(const float4*)(sv + e);
    float4 v1 = *(const float4*)(sv + e + 4);
    acc = fmaf(fast_tanh(bf2f(u[0] & 0xffffu) + h0v.x), v0.x, acc);
    acc = fmaf(fast_tanh(bf2f(u[0] >> 16)     + h0v.y), v0.y, acc);
    acc = fmaf(fast_tanh(bf2f(u[1] & 0xffffu) + h0v.z), v0.z, acc);
    acc = fmaf(fast_tanh(bf2f(u[1] >> 16)     + h0v.w), v0.w, acc);
    acc = fmaf(fast_tanh(bf2f(u[2] & 0xffffu) + h1v.x), v1.x, acc);
    acc = fmaf(fast_tanh(bf2f(u[2] >> 16)     + h1v.y), v1.y, acc);
    acc = fmaf(fast_tanh(bf2f(u[3] & 0xffffu) + h1v.z), v1.z, acc);
    acc = fmaf(fast_tanh(bf2f(u[3] >> 16)     + h1v.w), v1.w, acc);
    return acc;
}

// ---------------- output init: zero t=49 slices, write dec, reset barriers ----------------
__global__ void init_out_kernel(float* __restrict__ preds, float* __restrict__ alphas,
                                float* __restrict__ dec, const int* __restrict__ lens,
                                unsigned int* __restrict__ flags, unsigned int* __restrict__ go,
                                unsigned int* __restrict__ gflags)
{
    int i = blockIdx.x * 256 + threadIdx.x;
    if (i < NBLK_ * FSTRIDE) { flags[i] = 0u; gflags[i] = 0u; }
    if (i < NGO_ * FSTRIDE) go[i] = 0u;
    if (i < B_ * V_) {
        int b = i / V_, v = i - b * V_;
        preds[((size_t)b * TCAP_ + TMAX_) * V_ + v] = 0.f;
    }
    if (i < B_ * P_) {
        int b = i / P_, p = i - b * P_;
        alphas[((size_t)b * TCAP_ + TMAX_) * P_ + p] = 0.f;
    }
    if (i < B_) dec[i] = (float)(lens[i] - 1);
}

// ---------------- f32 -> bf16 cast (8 elems/thread) ----------------
__global__ void f2bf_kernel(const float* __restrict__ src, unsigned short* __restrict__ dst, int n8)
{
    int i = blockIdx.x * 256 + threadIdx.x;
    if (i >= n8) return;
    float4 a = ((const float4*)src)[2 * i];
    float4 b = ((const float4*)src)[2 * i + 1];
    uint4 o;
    o.x = (unsigned)f2bf_rne(a.x) | ((unsigned)f2bf_rne(a.y) << 16);
    o.y = (unsigned)f2bf_rne(a.z) | ((unsigned)f2bf_rne(a.w) << 16);
    o.z = (unsigned)f2bf_rne(b.x) | ((unsigned)f2bf_rne(b.y) << 16);
    o.w = (unsigned)f2bf_rne(b.z) | ((unsigned)f2bf_rne(b.w) << 16);
    ((uint4*)dst)[i] = o;
}

// ---------------- mean over P, output bf16 (64 x 2048) ----------------
__global__ void mean_kernel(const float* __restrict__ f, unsigned short* __restrict__ out)
{
    int i = blockIdx.x * 256 + threadIdx.x;
    int b = i >> 11, e = i & 2047;
    const float* p = f + (size_t)b * P_ * E_ + e;
    float s = 0.f;
    #pragma unroll 4
    for (int k = 0; k < P_; ++k) s += p[(size_t)k * E_];
    out[i] = f2bf_rne(s * (1.0f / (float)P_));
}

// ---------------- xwx GEMM, LDS-staged: 128x128 tile, BK=64 ----------------
__global__ void __launch_bounds__(256)
mfma_xwx_kernel(const unsigned short* __restrict__ A,   // [12544][2048]
                const unsigned short* __restrict__ W,   // [2048][2048]
                const float* __restrict__ bias,
                unsigned short* __restrict__ C)         // [12544][2048] bf16
{
    __shared__ unsigned short As[128 * 64];
    __shared__ unsigned short Bs[128 * 64];
    int wv = threadIdx.x >> 6, lane = threadIdx.x & 63;
    int mr = lane & 15, quad = lane >> 4;
    int m0 = blockIdx.y * 128;
    int n0 = blockIdx.x * 128;
    int wm = (wv & 1) * 64, wn = (wv >> 1) * 64;
    int srow = wv * 32;
    int lrow = lane >> 3;
    int lcol = (lane & 7) * 8;
    floatx4 acc[4][4] = {};
    for (int k0 = 0; k0 < E_; k0 += 64) {
        __syncthreads();
        #pragma unroll
        for (int i = 0; i < 4; ++i) {
            int r = srow + i * 8;
            __builtin_amdgcn_global_load_lds(
                (gptr_t)(A + (size_t)(m0 + r + lrow) * E_ + k0 + lcol),
                (lptr_t)(As + r * 64), 16, 0, 0);
            __builtin_amdgcn_global_load_lds(
                (gptr_t)(W + (size_t)(n0 + r + lrow) * E_ + k0 + lcol),
                (lptr_t)(Bs + r * 64), 16, 0, 0);
        }
        __syncthreads();
        #pragma unroll
        for (int kk = 0; kk < 64; kk += 32) {
            short8 af[4], bf[4];
            #pragma unroll
            for (int i = 0; i < 4; ++i)
                af[i] = *(const short8*)(As + (wm + i * 16 + mr) * 64 + kk + quad * 8);
            #pragma unroll
            for (int j = 0; j < 4; ++j)
                bf[j] = *(const short8*)(Bs + (wn + j * 16 + mr) * 64 + kk + quad * 8);
            #pragma unroll
            for (int i = 0; i < 4; ++i)
                #pragma unroll
                for (int j = 0; j < 4; ++j)
                    acc[i][j] = __builtin_amdgcn_mfma_f32_16x16x32_bf16(af[i], bf[j], acc[i][j], 0, 0, 0);
        }
    }
    #pragma unroll
    for (int j = 0; j < 4; ++j) {
        int col = n0 + wn + j * 16 + mr;
        float bs = bias[col];
        #pragma unroll
        for (int i = 0; i < 4; ++i) {
            int row = m0 + wm + i * 16 + quad * 4;
            #pragma unroll
            for (int ii = 0; ii < 4; ++ii)
                C[(size_t)(row + ii) * E_ + col] = f2bf_rne(acc[i][j][ii] + bs);
        }
    }
}

// ---------------- fc1 over all steps, LDS-staged: 128x128 tile, K=512 ----------------
__global__ void __launch_bounds__(256)
fc1tile_kernel(const unsigned short* __restrict__ Hall,  // [3136][512] (+OOB slack)
               const unsigned short* __restrict__ W,     // [10000][512] (+OOB slack)
               const float* __restrict__ bias,
               float* __restrict__ preds, const int* __restrict__ lens)
{
    __shared__ unsigned short As[128 * 64];
    __shared__ unsigned short Bs[128 * 64];
    int wv = threadIdx.x >> 6, lane = threadIdx.x & 63;
    int mr = lane & 15, quad = lane >> 4;
    int m0 = blockIdx.y * 128;
    int n0 = blockIdx.x * 128;
    int wm = (wv & 1) * 64, wn = (wv >> 1) * 64;
    int srow = wv * 32;
    int lrow = lane >> 3;
    int lcol = (lane & 7) * 8;
    floatx4 acc[4][4] = {};
    for (int k0 = 0; k0 < H_; k0 += 64) {
        __syncthreads();
        #pragma unroll
        for (int i = 0; i < 4; ++i) {
            int r = srow + i * 8;
            __builtin_amdgcn_global_load_lds(
                (gptr_t)(Hall + (size_t)(m0 + r + lrow) * H_ + k0 + lcol),
                (lptr_t)(As + r * 64), 16, 0, 0);
            __builtin_amdgcn_global_load_lds(
                (gptr_t)(W + (size_t)(n0 + r + lrow) * H_ + k0 + lcol),
                (lptr_t)(Bs + r * 64), 16, 0, 0);
        }
        __syncthreads();
        #pragma unroll
        for (int kk = 0; kk < 64; kk += 32) {
            short8 af[4], bf[4];
            #pragma unroll
            for (int i = 0; i < 4; ++i)
                af[i] = *(const short8*)(As + (wm + i * 16 + mr) * 64 + kk + quad * 8);
            #pragma unroll
            for (int j = 0; j < 4; ++j)
                bf[j] = *(const short8*)(Bs + (wn + j * 16 + mr) * 64 + kk + quad * 8);
            #pragma unroll
            for (int i = 0; i < 4; ++i)
                #pragma unroll
                for (int j = 0; j < 4; ++j)
                    acc[i][j] = __builtin_amdgcn_mfma_f32_16x16x32_bf16(af[i], bf[j], acc[i][j], 0, 0, 0);
        }
    }
    #pragma unroll
    for (int j = 0; j < 4; ++j) {
        int col = n0 + wn + j * 16 + mr;
        float bs = bias[min(col, V_ - 1)];
        #pragma unroll
        for (int i = 0; i < 4; ++i) {
            int row = m0 + wm + i * 16 + quad * 4;
            #pragma unroll
            for (int ii = 0; ii < 4; ++ii) {
                int r = row + ii;
                if (r < TMAX_ * B_ && col < V_) {
                    int t = r >> 6, b = r & 63;
                    float v = (lens[b] > t) ? (acc[i][j][ii] + bs) : 0.f;
                    preds[((size_t)b * TCAP_ + t) * V_ + col] = v;
                }
            }
        }
    }
}

// ---------------- skinny MFMA GEMM (used once for h0) ----------------
template<int KC>
__global__ void __launch_bounds__(256)
mfma_gemm64(const unsigned short* __restrict__ A, int ld,
            const unsigned short* __restrict__ W,
            const float* __restrict__ bias,
            float* __restrict__ C, unsigned short* __restrict__ Cbf, int ldc)
{
    int wv = threadIdx.x >> 6, lane = threadIdx.x & 63;
    int mr = lane & 15, quad = lane >> 4;
    int m0 = wv * 16;
    int n0 = blockIdx.x * 16;
    const unsigned short* pa = A + (size_t)(m0 + mr) * ld + quad * 8;
    const unsigned short* pb = W + (size_t)(n0 + mr) * ld + quad * 8;
    floatx4 acc = {0.f, 0.f, 0.f, 0.f};
    #pragma unroll 16
    for (int k0 = 0; k0 < KC; k0 += 32) {
        short8 a = *(const short8*)(const void*)(pa + k0);
        short8 b = *(const short8*)(const void*)(pb + k0);
        acc = __builtin_amdgcn_mfma_f32_16x16x32_bf16(a, b, acc, 0, 0, 0);
    }
    int col = n0 + mr;
    float bs = bias ? bias[col] : 0.f;
    #pragma unroll
    for (int i = 0; i < 4; ++i) {
        int row = m0 + quad * 4 + i;
        float v = acc[i] + bs;
        C[(size_t)row * ldc + col] = v;
        if (Cbf) Cbf[(size_t)row * ldc + col] = f2bf_rne(v);
    }
}

// ---------------- persistent fused recurrent loop ----------------
// 512 blocks x 256 threads (2 blocks/CU). Per step: 3 GLOBAL barriers + 1
// group barrier. Streaming phases B/C software-pipelined (2-deep, counted vmcnt).
__global__ void __launch_bounds__(256, 2)
loop_kernel(unsigned short* __restrict__ hbf,
            const unsigned short* __restrict__ whbf, const float* __restrict__ Wh_b,
            const unsigned short* __restrict__ fbbf, const float* __restrict__ fb_b,
            const unsigned short* __restrict__ ghhbf, const float* __restrict__ ghh_b,
            float* __restrict__ hwh, float* __restrict__ hf, float* __restrict__ gh,
            const unsigned short* __restrict__ xwx,
            const float* __restrict__ Vw, const float* __restrict__ Vb,
            float* __restrict__ lam,
            const unsigned short* __restrict__ fbf,
            const float* __restrict__ embed_w,
            const int* __restrict__ captions, const int* __restrict__ lens,
            unsigned short* __restrict__ inpbf,
            float* __restrict__ alphas,
            const unsigned short* __restrict__ wihbf, const float* __restrict__ b_ih,
            const float* __restrict__ h0,
            unsigned short* __restrict__ Hall,
            unsigned int* __restrict__ flags, unsigned int* __restrict__ go,
            unsigned int* __restrict__ gflags)
{
    __shared__ float smem[5376];   // 21 KiB: [0,3328) per-phase scratch, [3328,5376) = Vw
    float* sv = smem + 3328;
    const int bid = blockIdx.x;
    const int tid = threadIdx.x;
    const int wv = tid >> 6, lane = tid & 63;
    const int mr = lane & 15, quad = lane >> 4;
    unsigned int ep = 0;

    // Stage Vw once (immutable across steps); first B-sub __syncthreads orders it.
    {
        const float4* vs = (const float4*)Vw;
        ((float4*)sv)[tid]       = vs[tid];
        ((float4*)sv)[tid + 256] = vs[tid + 256];
    }

    // h state lives in a register of its owning phase-D thread (persistent blocks).
    float hreg = 0.f;
    if (bid < 128) {
        int row = tid >> 4, col = tid & 15;
        int b = (bid >> 5) * 16 + row, j = (bid & 31) * 16 + col;
        hreg = h0[(size_t)b * H_ + j];
    }

    for (int t = 0; t < TMAX_; ++t) {
        // ---------- phase A: hwh / hf / gh = h @ {Wh, f_beta, W_hh}^T ----------
        if (bid < 352) {
            const unsigned short* W; const float* bias; float* C; int n0; int ldc;
            if (bid < 128)      { W = whbf;  bias = Wh_b;  C = hwh; n0 = bid * 16;         ldc = E_; }
            else if (bid < 256) { W = fbbf;  bias = fb_b;  C = hf;  n0 = (bid - 128) * 16; ldc = E_; }
            else                { W = ghhbf; bias = ghh_b; C = gh;  n0 = (bid - 256) * 16; ldc = G3_; }
            int m0 = wv * 16;
            const unsigned short* pa = hbf + (size_t)(m0 + mr) * H_ + quad * 8;
            const unsigned short* pb = W + (size_t)(n0 + mr) * H_ + quad * 8;
            u32x4 av[16];
            GLD16(av[0],  pa, 0);    GLD16(av[1],  pa, 64);
            GLD16(av[2],  pa, 128);  GLD16(av[3],  pa, 192);
            GLD16(av[4],  pa, 256);  GLD16(av[5],  pa, 320);
            GLD16(av[6],  pa, 384);  GLD16(av[7],  pa, 448);
            GLD16(av[8],  pa, 512);  GLD16(av[9],  pa, 576);
            GLD16(av[10], pa, 640);  GLD16(av[11], pa, 704);
            GLD16(av[12], pa, 768);  GLD16(av[13], pa, 832);
            GLD16(av[14], pa, 896);  GLD16(av[15], pa, 960);
            asm volatile("s_waitcnt vmcnt(0)"
                : "+v"(av[0]), "+v"(av[1]), "+v"(av[2]),  "+v"(av[3]),
                  "+v"(av[4]), "+v"(av[5]), "+v"(av[6]),  "+v"(av[7]),
                  "+v"(av[8]), "+v"(av[9]), "+v"(av[10]), "+v"(av[11]),
                  "+v"(av[12]),"+v"(av[13]),"+v"(av[14]), "+v"(av[15])
                :: "memory");
            __builtin_amdgcn_sched_barrier(0);
            floatx4 acc0 = {0.f, 0.f, 0.f, 0.f};
            floatx4 acc1 = {0.f, 0.f, 0.f, 0.f};
            #pragma unroll
            for (int i = 0; i < 16; i += 2) {
                short8 b0 = *(const short8*)(const void*)(pb + i * 32);
                short8 b1 = *(const short8*)(const void*)(pb + i * 32 + 32);
                acc0 = __builtin_amdgcn_mfma_f32_16x16x32_bf16(cvt8(av[i]),     b0, acc0, 0, 0, 0);
                acc1 = __builtin_amdgcn_mfma_f32_16x16x32_bf16(cvt8(av[i + 1]), b1, acc1, 0, 0, 0);
            }
            floatx4 acc = acc0 + acc1;
            int col = n0 + mr;
            float bs = bias[col];
            #pragma unroll
            for (int i = 0; i < 4; ++i)
                stf(&C[(size_t)(m0 + quad * 4 + i) * ldc + col], acc[i] + bs);
        }
        gbar(flags, go, ++ep);

        // ---------- merged phase B+C (group-local lam handoff) ----------
        {
            int b = bid >> 3, q = bid & 7;
            // --- B-sub: lam[b,p] for p in q*25..q*25+24 (2-deep pipelined) ---
            float* sh = smem;          // hwh[b], 2048 f32
            const float* hsrc = hwh + (size_t)b * E_;
            u32x4 hv0, hv1;
            GLD16(hv0, hsrc + tid * 4, 0);
            GLD16(hv1, hsrc + 1024 + tid * 4, 0);
            asm volatile("s_waitcnt vmcnt(0)" : "+v"(hv0), "+v"(hv1) :: "memory");
            __builtin_amdgcn_sched_barrier(0);
            ((u32x4*)sh)[tid]       = hv0;
            ((u32x4*)sh)[tid + 256] = hv1;
            __syncthreads();
            float vb0 = Vb[0];
            {
                int p0 = q * 25 + wv;
                const unsigned short* px = xwx + ((size_t)b * P_ + p0) * E_ + lane * 8;
                u32x4 c0, c1, c2, c3, n0, n1, n2, n3;
                GLDC16(c0, px, 0);    GLDC16(c1, px, 1024);
                GLDC16(c2, px, 2048); GLDC16(c3, px, 3072);
                #pragma unroll
                for (int i = 0; i < 7; ++i) {
                    if (i < 6) {
                        const unsigned short* pn = px + (size_t)4 * E_;
                        GLDC16(n0, pn, 0);    GLDC16(n1, pn, 1024);
                        GLDC16(n2, pn, 2048); GLDC16(n3, pn, 3072);
                        px = pn;
                        asm volatile("s_waitcnt vmcnt(4)"
                            : "+v"(c0), "+v"(c1), "+v"(c2), "+v"(c3) :: "memory");
                    } else {
                        asm volatile("s_waitcnt vmcnt(0)"
                            : "+v"(c0), "+v"(c1), "+v"(c2), "+v"(c3) :: "memory");
                    }
                    __builtin_amdgcn_sched_barrier(0);
                    float acc = 0.f;
                    acc = brow_acc(c0, sh, sv, lane * 8, acc);
                    acc = brow_acc(c1, sh, sv, 512 + lane * 8, acc);
                    acc = brow_acc(c2, sh, sv, 1024 + lane * 8, acc);
                    acc = brow_acc(c3, sh, sv, 1536 + lane * 8, acc);
                    #pragma unroll
                    for (int off = 32; off > 0; off >>= 1) acc += __shfl_down(acc, off);
                    int pl = wv + i * 4, p = p0 + i * 4;
                    if (lane == 0 && pl < 25 && p < P_) stf(&lam[b * P_ + p], acc + vb0);
                    c0 = n0; c1 = n1; c2 = n2; c3 = n3;
                }
            }
            groupbar(gflags, (unsigned)(t + 1));
            // --- C-sub: softmax + z + gate + emb -> inpbf, alphas ---
            int c = q;
            int e0 = c * 256;
            float* sa = smem;          // 256: unnormalized exp (0 beyond P_)
            float* sr = smem + 256;    // 8:   wave partials
            float* ps = smem + 512;    // 2048: z partials [8][256]
            float x = (tid < P_) ? ldf(&lam[b * P_ + tid]) : -1e30f;
            float mxl = x;
            #pragma unroll
            for (int off = 32; off > 0; off >>= 1) mxl = fmaxf(mxl, __shfl_xor(mxl, off));
            if (lane == 0) sr[wv] = mxl;
            __syncthreads();
            float mx = fmaxf(fmaxf(sr[0], sr[1]), fmaxf(sr[2], sr[3]));
            float ex = (tid < P_) ? __expf(x - mx) : 0.f;
            sa[tid] = ex;
            float sml = ex;
            #pragma unroll
            for (int off = 32; off > 0; off >>= 1) sml += __shfl_xor(sml, off);
            if (lane == 0) sr[4 + wv] = sml;
            __syncthreads();
            float inv = 1.f / (sr[4] + sr[5] + sr[6] + sr[7]);
            if (c == 0 && tid < P_)
                alphas[(size_t)b * TCAP_ * P_ + (size_t)t * P_ + tid] = (lens[b] > t) ? ex * inv : 0.f;
            if (c == 1) {
                int cap = captions[b * TCAP_ + t];
                float2 v = *(const float2*)(embed_w + (size_t)cap * EMB_ + tid * 2);
                stu((u32*)(inpbf + (size_t)b * KI_ + E_) + tid,
                    (u32)f2bf_rne(v.x) | ((u32)f2bf_rne(v.y) << 16));
            }
            // z over 256 cols: 8 row-groups x 32 lanes x 8 cols, 16B/lane, 2-deep pipeline.
            // Rows beyond P_ read harmlessly (workspace slack); sa[p]=0 there.
            {
                int rg = tid >> 5;        // 0..7
                int l32 = tid & 31;       // 0..31
                const unsigned short* fp = fbf + ((size_t)b * P_ + rg) * E_ + e0 + l32 * 8;
                float a0=0.f,a1=0.f,a2=0.f,a3=0.f,a4=0.f,a5=0.f,a6=0.f,a7=0.f;
                u32x4 d0, d1, d2;
                GLDC16(d0, fp, 0);
                GLDC16(d1, fp + (size_t)8 * E_, 0);
                #pragma unroll
                for (int it = 0; it < 25; ++it) {
                    if (it < 23) {
                        GLDC16(d2, fp + (size_t)(it + 2) * 8 * E_, 0);
                        asm volatile("s_waitcnt vmcnt(2)" : "+v"(d0) :: "memory");
                    } else if (it == 23) {
                        asm volatile("s_waitcnt vmcnt(1)" : "+v"(d0) :: "memory");
                    } else {
                        asm volatile("s_waitcnt vmcnt(0)" : "+v"(d0) :: "memory");
                    }
                    __builtin_amdgcn_sched_barrier(0);
                    float wgt = sa[rg + it * 8];
                    a0 = fmaf(wgt, bf2f(d0[0] & 0xffffu), a0);
                    a1 = fmaf(wgt, bf2f(d0[0] >> 16),     a1);
                    a2 = fmaf(wgt, bf2f(d0[1] & 0xffffu), a2);
                    a3 = fmaf(wgt, bf2f(d0[1] >> 16),     a3);
                    a4 = fmaf(wgt, bf2f(d0[2] & 0xffffu), a4);
                    a5 = fmaf(wgt, bf2f(d0[2] >> 16),     a5);
                    a6 = fmaf(wgt, bf2f(d0[3] & 0xffffu), a6);
                    a7 = fmaf(wgt, bf2f(d0[3] >> 16),     a7);
                    d0 = d1; d1 = d2;
                }
                float* pw = ps + rg * 256 + l32 * 8;
                pw[0]=a0; pw[1]=a1; pw[2]=a2; pw[3]=a3;
                pw[4]=a4; pw[5]=a5; pw[6]=a6; pw[7]=a7;
            }
            __syncthreads();
            if (tid < 128) {
                int col = tid * 2;
                float z0 = 0.f, z1 = 0.f;
                #pragma unroll
                for (int r8 = 0; r8 < 8; ++r8) {
                    z0 += ps[r8 * 256 + col];
                    z1 += ps[r8 * 256 + col + 1];
                }
                z0 *= inv; z1 *= inv;
                float g0 = ldf(hf + (size_t)b * E_ + e0 + col);
                float g1 = ldf(hf + (size_t)b * E_ + e0 + col + 1);
                stu((u32*)(inpbf + (size_t)b * KI_ + e0) + tid,
                    (u32)f2bf_rne(fast_sig(g0) * z0) | ((u32)f2bf_rne(fast_sig(g1) * z1) << 16));
            }
        }
        gbar(flags, go, ++ep);

        // ---------- phase D: gi GEMM + GRU combine -> hreg, hbf, Hall ----------
        if (bid < 128) {
            float (*red)[3][16][17] = (float (*)[3][16][17])smem;  // 13 KiB
            int j0 = (bid & 31) * 16;
            int m0 = (bid >> 5) * 16;
            int koff = wv * 640;
            const unsigned short* pa  = inpbf + (size_t)(m0 + mr) * KI_ + koff + quad * 8;
            const unsigned short* pb0 = wihbf + (size_t)(j0 + mr) * KI_ + koff + quad * 8;
            const unsigned short* pb1 = pb0 + (size_t)512 * KI_;
            const unsigned short* pb2 = pb0 + (size_t)1024 * KI_;
            u32x4 av[20];
            GLD16(av[0],  pa, 0);     GLD16(av[1],  pa, 64);
            GLD16(av[2],  pa, 128);   GLD16(av[3],  pa, 192);
            GLD16(av[4],  pa, 256);   GLD16(av[5],  pa, 320);
            GLD16(av[6],  pa, 384);   GLD16(av[7],  pa, 448);
            GLD16(av[8],  pa, 512);   GLD16(av[9],  pa, 576);
            GLD16(av[10], pa, 640);   GLD16(av[11], pa, 704);
            GLD16(av[12], pa, 768);   GLD16(av[13], pa, 832);
            GLD16(av[14], pa, 896);   GLD16(av[15], pa, 960);
            GLD16(av[16], pa, 1024);  GLD16(av[17], pa, 1088);
            GLD16(av[18], pa, 1152);  GLD16(av[19], pa, 1216);
            asm volatile("s_waitcnt vmcnt(0)"
                : "+v"(av[0]), "+v"(av[1]), "+v"(av[2]),  "+v"(av[3]),
                  "+v"(av[4]), "+v"(av[5]), "+v"(av[6]),  "+v"(av[7]),
                  "+v"(av[8]), "+v"(av[9]), "+v"(av[10]), "+v"(av[11]),
                  "+v"(av[12]),"+v"(av[13]),"+v"(av[14]), "+v"(av[15]),
                  "+v"(av[16]),"+v"(av[17]),"+v"(av[18]), "+v"(av[19])
                :: "memory");
            __builtin_amdgcn_sched_barrier(0);
            floatx4 ar = {0.f,0.f,0.f,0.f}, az = {0.f,0.f,0.f,0.f}, an = {0.f,0.f,0.f,0.f};
            #pragma unroll
            for (int k = 0; k < 20; ++k) {
                short8 a  = cvt8(av[k]);
                short8 br = *(const short8*)(const void*)(pb0 + k * 32);
                short8 bz = *(const short8*)(const void*)(pb1 + k * 32);
                short8 bn = *(const short8*)(const void*)(pb2 + k * 32);
                ar = __builtin_amdgcn_mfma_f32_16x16x32_bf16(a, br, ar, 0, 0, 0);
                az = __builtin_amdgcn_mfma_f32_16x16x32_bf16(a, bz, az, 0, 0, 0);
                an = __builtin_amdgcn_mfma_f32_16x16x32_bf16(a, bn, an, 0, 0, 0);
            }
            #pragma unroll
            for (int i = 0; i < 4; ++i) {
                red[wv][0][quad * 4 + i][mr] = ar[i];
                red[wv][1][quad * 4 + i][mr] = az[i];
                red[wv][2][quad * 4 + i][mr] = an[i];
            }
            __syncthreads();
            int row = tid >> 4, col = tid & 15;
            int b = m0 + row, j = j0 + col;
            float ir = red[0][0][row][col] + red[1][0][row][col] + red[2][0][row][col] + red[3][0][row][col] + b_ih[j];
            float iz = red[0][1][row][col] + red[1][1][row][col] + red[2][1][row][col] + red[3][1][row][col] + b_ih[512 + j];
            float in_= red[0][2][row][col] + red[1][2][row][col] + red[2][2][row][col] + red[3][2][row][col] + b_ih[1024 + j];
            float hr = ldf(&gh[(size_t)b * G3_ + j]);
            float hz = ldf(&gh[(size_t)b * G3_ + 512 + j]);
            float hn = ldf(&gh[(size_t)b * G3_ + 1024 + j]);
            float r  = fast_sig(ir + hr);
            float zg = fast_sig(iz + hz);
            float n  = fast_tanh(in_ + r * hn);
            float hv = (1.f - zg) * n + zg * hreg;
            float ho = (lens[b] > t) ? hv : hreg;
            hreg = ho;
            unsigned short hob = f2bf_rne(ho);
            u32 nb = (u32)(unsigned short)__shfl_down((int)hob, 1);
            if ((tid & 1) == 0)
                stu((u32*)hbf + ((size_t)b * H_ + j) / 2, (u32)hob | (nb << 16));
            Hall[((size_t)t * B_ + b) * H_ + j] = hob;
        }
        gbar(flags, go, ++ep);
    }
}

extern "C" void kernel_launch(void* const* d_in, const int* in_sizes, int n_in,
                              void* d_out, int out_size, void* d_ws, size_t ws_size,
                              hipStream_t stream)
{
    const float* features  = (const float*)d_in[0];
    const int*   captions  = (const int*)d_in[1];
    const int*   lengths   = (const int*)d_in[2];
    const float* Wx_w      = (const float*)d_in[3];
    const float* Wx_b      = (const float*)d_in[4];
    const float* Wh_w      = (const float*)d_in[5];
    const float* Wh_b      = (const float*)d_in[6];
    const float* V_w       = (const float*)d_in[7];
    const float* V_b       = (const float*)d_in[8];
    const float* init_h_w  = (const float*)d_in[9];
    const float* init_h_b  = (const float*)d_in[10];
    const float* f_beta_w  = (const float*)d_in[11];
    const float* f_beta_b  = (const float*)d_in[12];
    const float* embed_w   = (const float*)d_in[13];
    const float* gru_w_ih  = (const float*)d_in[14];
    const float* gru_b_ih  = (const float*)d_in[15];
    const float* gru_w_hh  = (const float*)d_in[16];
    const float* gru_b_hh  = (const float*)d_in[17];
    const float* fc1_w     = (const float*)d_in[18];
    const float* fc1_b     = (const float*)d_in[19];

    float* preds  = (float*)d_out;
    float* alphas = preds + (size_t)B_ * TCAP_ * V_;
    float* dec    = alphas + (size_t)B_ * TCAP_ * P_;

    char* w = (char*)d_ws;
    unsigned short* fbf     = (unsigned short*)w; w += (size_t)12544 * 2048 * 2;
    unsigned short* xwx     = (unsigned short*)w; w += (size_t)12544 * 2048 * 2;
    unsigned short* wxbf    = (unsigned short*)w; w += (size_t)2048 * 2048 * 2;
    unsigned short* whbf    = (unsigned short*)w; w += (size_t)2048 * 512 * 2;
    unsigned short* fbbf    = (unsigned short*)w; w += (size_t)2048 * 512 * 2;
    unsigned short* ghhbf   = (unsigned short*)w; w += (size_t)1536 * 512 * 2;
    unsigned short* wihbf   = (unsigned short*)w; w += (size_t)1536 * 2560 * 2;
    unsigned short* fc1bf   = (unsigned short*)w; w += (size_t)10112 * 512 * 2;  // +slack for OOB tile reads
    unsigned short* ihwbf   = (unsigned short*)w; w += (size_t)512 * 2048 * 2;
    unsigned short* fmeanbf = (unsigned short*)w; w += (size_t)64 * 2048 * 2;
    unsigned short* hbf     = (unsigned short*)w; w += (size_t)64 * 512 * 2;
    unsigned short* inpbf   = (unsigned short*)w; w += (size_t)64 * KI_ * 2;
    unsigned short* Hall    = (unsigned short*)w; w += (size_t)3200 * 512 * 2;   // +slack rows
    float* h   = (float*)w; w += (size_t)64 * 512 * 4;
    float* hwh = (float*)w; w += (size_t)64 * 2048 * 4;
    float* hf  = (float*)w; w += (size_t)64 * 2048 * 4;
    float* gh  = (float*)w; w += (size_t)64 * 1536 * 4;
    float* lam = (float*)w; w += (size_t)64 * 196 * 4;
    unsigned int* flags  = (unsigned int*)w; w += (size_t)NBLK_ * FSTRIDE * 4;
    unsigned int* go     = (unsigned int*)w; w += (size_t)NGO_ * FSTRIDE * 4;
    unsigned int* gflags = (unsigned int*)w; w += (size_t)NBLK_ * FSTRIDE * 4;

    init_out_kernel<<<2500, 256, 0, stream>>>(preds, alphas, dec, lengths, flags, go, gflags);

    f2bf_kernel<<<12544, 256, 0, stream>>>(features, fbf, 12544 * 2048 / 8);
    f2bf_kernel<<<2048, 256, 0, stream>>>(Wx_w, wxbf, 2048 * 2048 / 8);
    f2bf_kernel<<<512, 256, 0, stream>>>(Wh_w, whbf, 2048 * 512 / 8);
    f2bf_kernel<<<512, 256, 0, stream>>>(f_beta_w, fbbf, 2048 * 512 / 8);
    f2bf_kernel<<<384, 256, 0, stream>>>(gru_w_hh, ghhbf, 1536 * 512 / 8);
    f2bf_kernel<<<1920, 256, 0, stream>>>(gru_w_ih, wihbf, 1536 * 2560 / 8);
    f2bf_kernel<<<2500, 256, 0, stream>>>(fc1_w, fc1bf, 10000 * 512 / 8);
    f2bf_kernel<<<512, 256, 0, stream>>>(init_h_w, ihwbf, 512 * 2048 / 8);

    mean_kernel<<<512, 256, 0, stream>>>(features, fmeanbf);
    mfma_gemm64<2048><<<32, 256, 0, stream>>>(fmeanbf, 2048, ihwbf, init_h_b, h, hbf, 512);
    mfma_xwx_kernel<<<dim3(16, 98), 256, 0, stream>>>(fbf, wxbf, Wx_b, xwx);

    loop_kernel<<<NBLK_, 256, 0, stream>>>(hbf, whbf, Wh_b, fbbf, f_beta_b, ghhbf, gru_b_hh,
                                           hwh, hf, gh, xwx, V_w, V_b, lam, fbf, embed_w,
                                           captions, lengths, inpbf, alphas, wihbf, gru_b_ih,
                                           h, Hall, flags, go, gflags);

    fc1tile_kernel<<<dim3(79, 25), 256, 0, stream>>>(Hall, fc1bf, fc1_b, preds, lengths);
}